// Round 11
// baseline (4346.002 us; speedup 1.0000x reference)
//
#include <hip/hip_runtime.h>
#include <hip/hip_cooperative_groups.h>

namespace cg = cooperative_groups;

#define NB 262144
#define NT 64
#define NSTEP 63
#define DTF (1.0f/64.0f)
#define DTD (1.0/64.0)
#define RRF 0.05f
#define INV_B (1.0/262144.0)
#define ACC_STRIDE 48
#define NSL 8
#define BLOCKS 256
#define TPB 256
#define PPT 4
#define PSTRIDE (BLOCKS*TPB)   // 65536, 4 paths/thread

// ws layout (bytes)
#define ACC_BYTES   196608                      // 64*8*48 doubles
#define FLAG_OFF    ACC_BYTES
#define FLAG_BYTES  4096                        // 8 arrival ctrs + 8 release words (64B apart)
#define DWT_OFF     (FLAG_OFF + FLAG_BYTES)
#define DWT_BYTES   (63*NB*4)
#define ST_OFF      (DWT_OFF + DWT_BYTES)
#define ST_BYTES    (64*NB*4)
#define H2_OFF      (ST_OFF + ST_BYTES)          // fallback-only scratch
#define WS_NEED     ((size_t)ST_OFF + (size_t)ST_BYTES)

#define ALOADD(p) __hip_atomic_load((double*)(p), __ATOMIC_RELAXED, __HIP_MEMORY_SCOPE_AGENT)

struct KP {
    const float *Wraw, *Sraw, *dWt, *St;
    double* acc; unsigned int* fl; float* out;
    const float *g0,*b0,*W0,*g1,*b1,*W1,*g2,*b2,*W2,*bias2,*g3,*b3;
    const float *y0i,*y1i,*z0i,*z1i;
};

__global__ void kinit(double* __restrict__ z) {
    int i = blockIdx.x * 256 + threadIdx.x;
    if (i < (int)((ACC_BYTES + FLAG_BYTES) / 8)) z[i] = 0.0;
}

__global__ __launch_bounds__(256) void ktrans(const float* __restrict__ in,
                                              float* __restrict__ out, int diffmode) {
    __shared__ float tile[64][65];
    const int b0 = blockIdx.x * 64;
    const int tx = threadIdx.x & 63;
    const int ty = threadIdx.x >> 6;
    #pragma unroll
    for (int i = 0; i < 16; ++i) {
        int p = ty * 16 + i;
        tile[p][tx] = in[(size_t)(b0 + p) * NT + tx];
    }
    __syncthreads();
    if (diffmode) {
        #pragma unroll
        for (int i = 0; i < 16; ++i) {
            int tt = ty * 16 + i;
            if (tt < 63) out[(size_t)tt * NB + b0 + tx] = tile[tx][tt + 1] - tile[tx][tt];
        }
    } else {
        #pragma unroll
        for (int i = 0; i < 16; ++i) {
            int tt = ty * 16 + i;
            out[(size_t)tt * NB + b0 + tx] = tile[tx][tt];
        }
    }
}

// block-level reduce of K doubles, one f64 atomic per value into block's slice.
template<int K>
__device__ __forceinline__ void bred(const double* v, double (*red)[22],
                                     double* target, int tid) {
    const int lane = tid & 63;
    const int wave = tid >> 6;
    #pragma unroll
    for (int k = 0; k < K; ++k) {
        double x = v[k];
        #pragma unroll
        for (int off = 32; off > 0; off >>= 1) x += __shfl_xor(x, off, 64);
        if (lane == 0) red[wave][k] = x;
    }
    __syncthreads();
    if (tid < K) {
        double s = red[0][tid] + red[1][tid] + red[2][tid] + red[3][tid];
        atomicAdd(&target[tid], s);
    }
}

// FENCELESS grid barrier with DISTRIBUTED release words.
// All cross-block data flows through coherence-point atomics, so no cache
// wb/inv is needed. Hot-line fix vs round 10: 8 release copies (64B apart);
// block 0's leader wave verifies all 8 arrival ctrs via __all, lanes 0-7
// then write the 8 copies; each other block polls only copy (bid&7) with
// s_sleep backoff -> ~31 pollers/line instead of 255 on one line.
__device__ __forceinline__ void gbar(unsigned int* fl, unsigned int gen) {
    __syncthreads();
    if (threadIdx.x == 0) {
        asm volatile("s_waitcnt vmcnt(0)" ::: "memory");
        __hip_atomic_fetch_add(&fl[(blockIdx.x & 7) * 16], 1u,
                               __ATOMIC_RELAXED, __HIP_MEMORY_SCOPE_AGENT);
    }
    if (blockIdx.x == 0) {
        if (threadIdx.x < 64) {
            for (;;) {
                unsigned int c = __hip_atomic_load(&fl[(threadIdx.x & 7) * 16],
                    __ATOMIC_RELAXED, __HIP_MEMORY_SCOPE_AGENT);
                if (__all(c >= gen * 32u)) break;
                __builtin_amdgcn_s_sleep(1);
            }
            asm volatile("" ::: "memory");
            if (threadIdx.x < 8)
                __hip_atomic_store(&fl[128 + threadIdx.x * 16], gen,
                                   __ATOMIC_RELAXED, __HIP_MEMORY_SCOPE_AGENT);
        }
    } else if (threadIdx.x == 0) {
        const int rw = 128 + (blockIdx.x & 7) * 16;
        while (__hip_atomic_load(&fl[rw], __ATOMIC_RELAXED,
                                 __HIP_MEMORY_SCOPE_AGENT) < gen)
            __builtin_amdgcn_s_sleep(2);
        asm volatile("" ::: "memory");
    }
    __syncthreads();
}

// ================= persistent single-kernel path =================
// 2 barriers/step: phase-A moments are reconstructed analytically from 20
// symbolic sums (state update is affine in z0,z1) reduced during prior C.

template<bool TR>
__global__ __launch_bounds__(256) void kmain(KP p) {
    const int tid = threadIdx.x;
    const int bid = blockIdx.x;
    const int gid = bid * TPB + tid;
    const int sl  = bid & (NSL - 1);
    double* acc = p.acc;
    unsigned int gen = 0;
    #define ACCS(t, q) (acc + ((size_t)(t) * NSL + (q)) * ACC_STRIDE)

    __shared__ float  cf[64];
    __shared__ double red[4][22];
    __shared__ double asum[24];

    float x0[PPT], x1[PPT], y0[PPT], y1[PPT];
    float A0[PPT], A1[PPT], A2[PPT], A3[PPT];
    float dwr[PPT], sr[PPT];
    float h2p[PPT][11];

    // ---------- prologue: step-0 update with z_init + direct 14-moment reduce ----------
    {
        const float z0f = p.z0i[0], z1f = p.z1i[0];
        const float yi0 = p.y0i[0], yi1 = p.y1i[0];
        double v14[14];
        #pragma unroll
        for (int k = 0; k < 14; ++k) v14[k] = 0.0;
        #pragma unroll
        for (int pp = 0; pp < PPT; ++pp) {
            const int pb = gid + pp * PSTRIDE;
            float dw, s;
            if (TR) { dw = p.dWt[pb]; s = p.St[pb]; }
            else {
                const float* wr = p.Wraw + (size_t)pb * NT;
                dw = wr[1] - wr[0]; s = p.Sraw[(size_t)pb * NT];
            }
            dwr[pp] = dw; sr[pp] = s;
            float ox0 = 1.f, ox1 = 0.f, oy0 = yi0, oy1 = yi1;
            float x0n = ox0 + (0.05f*s*ox0 + 0.01f*s*ox1)*DTF
                            + (0.2f*s*ox0 + 0.1f*s*ox1)*dw;
            float y0n = oy0 + RRF*oy0*DTF + z0f*dw;
            float y1n = oy1 + RRF*oy1*DTF + z1f*dw;
            float x1n = ox1 - y1n*DTF;
            x0[pp] = x0n; x1[pp] = x1n; y0[pp] = y0n; y1[pp] = y1n;
            double d0 = x0n, d1 = x1n, d2 = y0n, d3 = y1n;
            v14[0] += d0;    v14[1] += d1;    v14[2] += d2;    v14[3] += d3;
            v14[4] += d0*d0; v14[5] += d0*d1; v14[6] += d0*d2; v14[7] += d0*d3;
            v14[8] += d1*d1; v14[9] += d1*d2; v14[10]+= d1*d3;
            v14[11]+= d2*d2; v14[12]+= d2*d3; v14[13]+= d3*d3;
        }
        bred<14>(v14, red, ACCS(0, sl), tid);
        gbar(p.fl, ++gen);
    }

    #pragma unroll 1
    for (int t = 0; t < NSTEP; ++t) {
        // ---------- phase B: stage sums -> (reconstruct) -> coefs -> h1/h2pre + 22 reduce ----------
        if (t == 0) {
            if (tid < 14) {
                double s = 0.0;
                #pragma unroll
                for (int q = 0; q < NSL; ++q) s += ALOADD(ACCS(0,q) + tid);
                asum[tid] = s;
            }
        } else {
            if (tid < 22) {
                double s = 0.0;
                #pragma unroll
                for (int q = 0; q < NSL; ++q) s += ALOADD(ACCS(t,q) + tid);
                asum[tid] = s;
            } else if (tid == 22) asum[22] = ALOADD(ACCS(t,0) + 44);
            else if   (tid == 23) asum[23] = ALOADD(ACCS(t,0) + 45);
        }
        __syncthreads();
        if (tid < 12) {
            double M1[4], P[10];
            if (t == 0) {
                #pragma unroll
                for (int i = 0; i < 4; ++i) M1[i] = asum[i];
                #pragma unroll
                for (int k = 0; k < 10; ++k) P[k] = asum[4 + k];
            } else {
                double m3 = asum[20] * INV_B;
                double v3 = asum[21] * INV_B - m3 * m3; v3 = v3 < 0.0 ? 0.0 : v3;
                double r3 = 1.0 / sqrt(v3 + 1e-6);
                double g  = (double)p.g3[t-1], bb = (double)p.b3[t-1];
                double z0d = g * (asum[22] - m3) * r3 + bb;
                double z1d = g * (asum[23] - m3) * r3 + bb;
                if (tid == 0) { cf[62] = (float)z0d; cf[63] = (float)z1d; }
                double Sd = asum[18], Sd2 = asum[19];
                M1[0] = asum[0];
                M1[1] = asum[1] - z1d*DTD*Sd;
                M1[2] = asum[2] + z0d*Sd;
                M1[3] = asum[3] + z1d*Sd;
                P[0] = asum[4];
                P[1] = asum[5] - z1d*DTD*asum[14];
                P[2] = asum[6] + z0d*asum[14];
                P[3] = asum[7] + z1d*asum[14];
                P[4] = asum[8] - 2.0*z1d*DTD*asum[15] + z1d*z1d*DTD*DTD*Sd2;
                P[5] = asum[9] + z0d*asum[15] - z1d*DTD*asum[16] - z0d*z1d*DTD*Sd2;
                P[6] = asum[10] + z1d*asum[15] - z1d*DTD*asum[17] - z1d*z1d*DTD*Sd2;
                P[7] = asum[11] + 2.0*z0d*asum[16] + z0d*z0d*Sd2;
                P[8] = asum[12] + z1d*asum[16] + z0d*asum[17] + z0d*z1d*Sd2;
                P[9] = asum[13] + 2.0*z1d*asum[17] + z1d*z1d*Sd2;
            }
            double m[4];
            #pragma unroll
            for (int i = 0; i < 4; ++i) m[i] = M1[i] * INV_B;
            double C[4][4];
            {
                int pidx = 0;
                #pragma unroll
                for (int i = 0; i < 4; ++i)
                    #pragma unroll
                    for (int k = i; k < 4; ++k) {
                        double c = P[pidx++] * INV_B - m[i] * m[k];
                        C[i][k] = c; C[k][i] = c;
                    }
            }
            double u[4];
            #pragma unroll
            for (int i = 0; i < 4; ++i) {
                double vi = C[i][i]; vi = vi < 0.0 ? 0.0 : vi;
                u[i] = (double)p.g0[(size_t)t*4 + i] / sqrt(vi + 1e-6);
            }
            if (tid == 11) {
                #pragma unroll
                for (int i = 0; i < 4; ++i) {
                    cf[0 + i] = (float)u[i];
                    cf[4 + i] = (float)m[i];
                    cf[8 + i] = p.b0[(size_t)t*4 + i];
                }
            } else {
                const int j = tid;
                const float* w0 = p.W0 + (size_t)t * 44;
                double mj = 0.0, vj = 0.0;
                #pragma unroll
                for (int i = 0; i < 4; ++i) {
                    double wij = (double)w0[i*11 + j];
                    mj += (double)p.b0[(size_t)t*4 + i] * wij;
                    double ti = 0.0;
                    #pragma unroll
                    for (int k = 0; k < 4; ++k) ti += u[i]*u[k]*C[i][k]*(double)w0[k*11 + j];
                    vj += wij * ti;
                }
                vj = vj < 0.0 ? 0.0 : vj;
                cf[12 + j] = (float)mj;
                cf[23 + j] = (float)((double)p.g1[(size_t)t*11 + j] / sqrt(vj + 1e-6));
                cf[34 + j] = p.b1[(size_t)t*11 + j];
            }
        }
        __syncthreads();
        if (t > 0) {
            const float zf0 = cf[62], zf1 = cf[63];
            #pragma unroll
            for (int pp = 0; pp < PPT; ++pp) {
                x0[pp] = A0[pp];
                y0[pp] = A2[pp] + zf0 * dwr[pp];
                y1[pp] = A3[pp] + zf1 * dwr[pp];
                x1[pp] = A1[pp] - zf1 * DTF * dwr[pp];
            }
        }
        {
            const float* w0 = p.W0 + (size_t)t * 44;
            const float* w1 = p.W1 + (size_t)t * 121;
            double v22[22];
            #pragma unroll
            for (int k = 0; k < 22; ++k) v22[k] = 0.0;
            #pragma unroll
            for (int pp = 0; pp < PPT; ++pp) {
                float h0[4] = { cf[0]*(x0[pp]-cf[4]) + cf[8],
                                cf[1]*(x1[pp]-cf[5]) + cf[9],
                                cf[2]*(y0[pp]-cf[6]) + cf[10],
                                cf[3]*(y1[pp]-cf[7]) + cf[11] };
                float h1[11];
                #pragma unroll
                for (int j = 0; j < 11; ++j) {
                    float hp = h0[0]*w0[j] + h0[1]*w0[11+j] + h0[2]*w0[22+j] + h0[3]*w0[33+j];
                    h1[j] = fmaxf(cf[23+j]*(hp - cf[12+j]) + cf[34+j], 0.f);
                }
                #pragma unroll
                for (int j = 0; j < 11; ++j) {
                    float hp = 0.f;
                    #pragma unroll
                    for (int i = 0; i < 11; ++i) hp += h1[i] * w1[i*11 + j];
                    h2p[pp][j] = hp;
                    double hd = hp;
                    v22[j] += hd; v22[11+j] += hd*hd;
                }
            }
            bred<22>(v22, red, ACCS(t, sl) + 22, tid);
        }
        gbar(p.fl, ++gen);

        // ---------- phase C: coefs2 -> h3 + symbolic 20 for step t+1 + h3 stats ----------
        if (tid < 22) {
            double s = 0.0;
            #pragma unroll
            for (int q = 0; q < NSL; ++q) s += ALOADD(ACCS(t,q) + 22 + tid);
            asum[tid] = s;
        }
        __syncthreads();
        if (tid < 11) {
            const int j = tid;
            double mj = asum[j] * INV_B;
            double vj = asum[11 + j] * INV_B - mj*mj; vj = vj < 0.0 ? 0.0 : vj;
            cf[j]      = (float)mj;
            cf[11 + j] = (float)((double)p.g2[(size_t)t*11 + j] / sqrt(vj + 1e-6));
            cf[22 + j] = p.b2[(size_t)t*11 + j];
            cf[33 + j] = p.W2[(size_t)t*11 + j];
            if (j == 0) cf[44] = p.bias2[t];
        }
        __syncthreads();
        {
            float h3v[PPT];
            #pragma unroll
            for (int pp = 0; pp < PPT; ++pp) {
                const int pb = gid + pp * PSTRIDE;
                float h3 = cf[44];
                #pragma unroll
                for (int j = 0; j < 11; ++j)
                    h3 += fmaxf(cf[11+j]*(h2p[pp][j] - cf[j]) + cf[22+j], 0.f) * cf[33+j];
                h3v[pp] = h3;
                if (pb == 0) atomicAdd(ACCS(t+1,0) + 44, (double)h3);
                if (pb == 1) atomicAdd(ACCS(t+1,0) + 45, (double)h3);
            }
            if (t < NSTEP - 1) {
                double v22[22];
                #pragma unroll
                for (int k = 0; k < 22; ++k) v22[k] = 0.0;
                #pragma unroll
                for (int pp = 0; pp < PPT; ++pp) {
                    const int pb = gid + pp * PSTRIDE;
                    float dw, s;
                    if (TR) {
                        dw = p.dWt[(size_t)(t+1) * NB + pb];
                        s  = p.St [(size_t)(t+1) * NB + pb];
                    } else {
                        const float* wr = p.Wraw + (size_t)pb * NT + (t+1);
                        dw = wr[1] - wr[0]; s = p.Sraw[(size_t)pb * NT + (t+1)];
                    }
                    dwr[pp] = dw; sr[pp] = s;
                    float a0 = x0[pp] + (0.05f*s*x0[pp] + 0.01f*s*x1[pp])*DTF
                                      + (0.2f*s*x0[pp] + 0.1f*s*x1[pp])*dw;
                    float a2 = y0[pp] + RRF*y0[pp]*DTF;
                    float a3 = y1[pp] + RRF*y1[pp]*DTF;
                    float a1 = x1[pp] - a3*DTF;
                    A0[pp]=a0; A1[pp]=a1; A2[pp]=a2; A3[pp]=a3;
                    double d0=a0, d1=a1, d2=a2, d3=a3, dd=dw;
                    v22[0] += d0;    v22[1] += d1;    v22[2] += d2;    v22[3] += d3;
                    v22[4] += d0*d0; v22[5] += d0*d1; v22[6] += d0*d2; v22[7] += d0*d3;
                    v22[8] += d1*d1; v22[9] += d1*d2; v22[10]+= d1*d3;
                    v22[11]+= d2*d2; v22[12]+= d2*d3; v22[13]+= d3*d3;
                    v22[14]+= d0*dd; v22[15]+= d1*dd; v22[16]+= d2*dd; v22[17]+= d3*dd;
                    v22[18]+= dd;    v22[19]+= dd*dd;
                    double h3d = h3v[pp];
                    v22[20]+= h3d;   v22[21]+= h3d*h3d;
                }
                bred<22>(v22, red, ACCS(t+1, sl), tid);
            } else {
                double v2[2] = {0.0, 0.0};
                #pragma unroll
                for (int pp = 0; pp < PPT; ++pp) {
                    double h3d = h3v[pp];
                    v2[0] += h3d; v2[1] += h3d*h3d;
                }
                bred<2>(v2, red, ACCS(NSTEP, sl) + 20, tid);
            }
        }
        gbar(p.fl, ++gen);
    }

    // ---------- final half-step ----------
    if (tid == 0) {
        double s20 = 0.0, s21 = 0.0;
        #pragma unroll
        for (int q = 0; q < NSL; ++q) {
            s20 += ALOADD(ACCS(NSTEP,q) + 20);
            s21 += ALOADD(ACCS(NSTEP,q) + 21);
        }
        double m3 = s20 * INV_B;
        double v3 = s21 * INV_B - m3*m3; v3 = v3 < 0.0 ? 0.0 : v3;
        double r3 = 1.0 / sqrt(v3 + 1e-6);
        double g = (double)p.g3[62], bb = (double)p.b3[62];
        cf[0] = (float)(g * (ALOADD(ACCS(NSTEP,0) + 44) - m3) * r3 + bb);
        cf[1] = (float)(g * (ALOADD(ACCS(NSTEP,0) + 45) - m3) * r3 + bb);
    }
    __syncthreads();
    {
        const float z0f = cf[0], z1f = cf[1];
        #pragma unroll
        for (int pp = 0; pp < PPT; ++pp) {
            const int pb = gid + pp * PSTRIDE;
            float dw = dwr[pp];   // inputs(62) retained: W[:,63]-W[:,62]
            float s;
            if (TR) s = p.St[(size_t)63 * NB + pb];
            else    s = p.Sraw[(size_t)pb * NT + 63];
            float x0n = x0[pp] + (0.05f*s*x0[pp] + 0.01f*s*x1[pp])*DTF
                               + (0.2f*s*x0[pp] + 0.1f*s*x1[pp])*dw;
            float y0n = y0[pp] + RRF*y0[pp]*DTF + z0f*dw;
            float y1n = y1[pp] + RRF*y1[pp]*DTF + z1f*(-dw);
            float x1n = x1[pp] - y1n*DTF;
            p.out[pb]          = x0n;
            p.out[NB + pb]     = x1n;
            p.out[2*NB + pb]   = y0n;
            p.out[3*NB + pb]   = y1n;
        }
    }
    #undef ACCS
}

// ================= fallback multi-kernel path (round-2, proven) =================

template<bool TR>
__global__ __launch_bounds__(256) void kA(
    const float* __restrict__ Wraw, const float* __restrict__ Sraw,
    const float* __restrict__ dWt,  const float* __restrict__ St,
    float4* __restrict__ state, double* __restrict__ acc, int t,
    const float* __restrict__ g3, const float* __restrict__ b3,
    const float* __restrict__ y0i, const float* __restrict__ y1i,
    const float* __restrict__ z0i, const float* __restrict__ z1i)
{
    __shared__ double red[4][22];
    const int b = blockIdx.x * 256 + threadIdx.x;
    float dw, s;
    if (TR) { dw = dWt[(size_t)t * NB + b]; s = St[(size_t)t * NB + b]; }
    else {
        const float* wr = Wraw + (size_t)b * NT + t;
        dw = wr[1] - wr[0]; s = Sraw[(size_t)b * NT + t];
    }
    float z0, z1, x0, x1, y0, y1;
    if (t == 0) {
        z0 = z0i[0]; z1 = z1i[0];
        x0 = 1.f; x1 = 0.f; y0 = y0i[0]; y1 = y1i[0];
    } else {
        const double* a = acc + (size_t)(t - 1) * ACC_STRIDE;
        double m3 = a[36] * INV_B;
        double v3 = a[37] * INV_B - m3 * m3; v3 = v3 < 0.0 ? 0.0 : v3;
        double r3 = 1.0 / sqrt(v3 + 1e-6);
        double g  = (double)g3[t - 1], bb = (double)b3[t - 1];
        z0 = (float)(g * (a[38] - m3) * r3 + bb);
        z1 = (float)(g * (a[39] - m3) * r3 + bb);
        float4 s4 = state[b];
        x0 = s4.x; x1 = s4.y; y0 = s4.z; y1 = s4.w;
    }
    float x0n = x0 + (0.05f*s*x0 + 0.01f*s*x1)*DTF + (0.2f*s*x0 + 0.1f*s*x1)*dw;
    float y0n = y0 + RRF*y0*DTF + z0*dw;
    float y1n = y1 + RRF*y1*DTF + z1*dw;
    float x1n = x1 - y1n*DTF;
    state[b] = make_float4(x0n, x1n, y0n, y1n);
    double d0 = x0n, d1 = x1n, d2 = y0n, d3 = y1n;
    double v[14] = { d0, d1, d2, d3,
                     d0*d0, d0*d1, d0*d2, d0*d3,
                     d1*d1, d1*d2, d1*d3,
                     d2*d2, d2*d3, d3*d3 };
    bred<14>(v, red, acc + (size_t)t * ACC_STRIDE, threadIdx.x);
}

__global__ __launch_bounds__(256) void kB(
    const float4* __restrict__ state, float* __restrict__ h2pre,
    double* __restrict__ acc, int t,
    const float* __restrict__ g0, const float* __restrict__ b0,
    const float* __restrict__ W0,
    const float* __restrict__ g1, const float* __restrict__ b1,
    const float* __restrict__ W1)
{
    __shared__ double red[4][22];
    const int b = blockIdx.x * 256 + threadIdx.x;
    float4 s4 = state[b];

    const double* a = acc + (size_t)t * ACC_STRIDE;
    double m[4];
    #pragma unroll
    for (int i = 0; i < 4; ++i) m[i] = a[i] * INV_B;
    double C[4][4];
    {
        int p = 4;
        #pragma unroll
        for (int i = 0; i < 4; ++i)
            #pragma unroll
            for (int k = i; k < 4; ++k) {
                double c = a[p++] * INV_B - m[i] * m[k];
                C[i][k] = c; C[k][i] = c;
            }
    }
    const float* w0 = W0 + (size_t)t * 44;
    float w0f[4][11];
    #pragma unroll
    for (int i = 0; i < 4; ++i)
        #pragma unroll
        for (int j = 0; j < 11; ++j) w0f[i][j] = w0[i * 11 + j];

    double u[4]; float uf[4], mf[4], b0f[4];
    #pragma unroll
    for (int i = 0; i < 4; ++i) {
        double vi = C[i][i]; vi = vi < 0.0 ? 0.0 : vi;
        double ri = 1.0 / sqrt(vi + 1e-6);
        u[i]  = (double)g0[(size_t)t * 4 + i] * ri;
        uf[i] = (float)u[i];
        mf[i] = (float)m[i];
        b0f[i] = b0[(size_t)t * 4 + i];
    }
    double M[4][4];
    #pragma unroll
    for (int i = 0; i < 4; ++i)
        #pragma unroll
        for (int k = 0; k < 4; ++k) M[i][k] = u[i] * u[k] * C[i][k];

    float mean1[11], q1[11], b1f[11];
    #pragma unroll
    for (int j = 0; j < 11; ++j) {
        double mj = 0.0, vj = 0.0;
        #pragma unroll
        for (int i = 0; i < 4; ++i) {
            mj += (double)b0f[i] * (double)w0f[i][j];
            double ti = 0.0;
            #pragma unroll
            for (int k = 0; k < 4; ++k) ti += M[i][k] * (double)w0f[k][j];
            vj += (double)w0f[i][j] * ti;
        }
        vj = vj < 0.0 ? 0.0 : vj;
        double rj = 1.0 / sqrt(vj + 1e-6);
        mean1[j] = (float)mj;
        q1[j]    = (float)((double)g1[(size_t)t * 11 + j] * rj);
        b1f[j]   = b1[(size_t)t * 11 + j];
    }

    float h0[4] = { uf[0]*(s4.x - mf[0]) + b0f[0],
                    uf[1]*(s4.y - mf[1]) + b0f[1],
                    uf[2]*(s4.z - mf[2]) + b0f[2],
                    uf[3]*(s4.w - mf[3]) + b0f[3] };
    float h1[11];
    #pragma unroll
    for (int j = 0; j < 11; ++j) {
        float hp = h0[0]*w0f[0][j] + h0[1]*w0f[1][j] + h0[2]*w0f[2][j] + h0[3]*w0f[3][j];
        h1[j] = fmaxf(q1[j] * (hp - mean1[j]) + b1f[j], 0.f);
    }
    const float* w1 = W1 + (size_t)t * 121;
    double v[22];
    #pragma unroll
    for (int j = 0; j < 11; ++j) {
        float hp = 0.f;
        #pragma unroll
        for (int i = 0; i < 11; ++i) hp += h1[i] * w1[i * 11 + j];
        h2pre[(size_t)j * NB + b] = hp;
        double hd = hp;
        v[j] = hd; v[11 + j] = hd * hd;
    }
    bred<22>(v, red, acc + (size_t)t * ACC_STRIDE + 14, threadIdx.x);
}

__global__ __launch_bounds__(256) void kC(
    const float* __restrict__ h2pre, double* __restrict__ acc, int t,
    const float* __restrict__ g2, const float* __restrict__ b2,
    const float* __restrict__ W2, const float* __restrict__ bias2)
{
    __shared__ double red[4][22];
    const int b = blockIdx.x * 256 + threadIdx.x;
    const double* a = acc + (size_t)t * ACC_STRIDE;
    float m2f[11], q2[11], b2f[11], w2f[11];
    #pragma unroll
    for (int j = 0; j < 11; ++j) {
        double mj = a[14 + j] * INV_B;
        double vj = a[25 + j] * INV_B - mj * mj; vj = vj < 0.0 ? 0.0 : vj;
        double rj = 1.0 / sqrt(vj + 1e-6);
        m2f[j] = (float)mj;
        q2[j]  = (float)((double)g2[(size_t)t * 11 + j] * rj);
        b2f[j] = b2[(size_t)t * 11 + j];
        w2f[j] = W2[(size_t)t * 11 + j];
    }
    float h3 = bias2[t];
    #pragma unroll
    for (int j = 0; j < 11; ++j) {
        float hv = h2pre[(size_t)j * NB + b];
        float h2 = fmaxf(q2[j] * (hv - m2f[j]) + b2f[j], 0.f);
        h3 += h2 * w2f[j];
    }
    double* aw = acc + (size_t)t * ACC_STRIDE;
    if (b == 0) aw[38] = (double)h3;
    if (b == 1) aw[39] = (double)h3;
    double hd = h3;
    double v[2] = { hd, hd * hd };
    bred<2>(v, red, aw + 36, threadIdx.x);
}

template<bool TR>
__global__ __launch_bounds__(256) void kF(
    const float* __restrict__ Wraw, const float* __restrict__ Sraw,
    const float* __restrict__ dWt,  const float* __restrict__ St,
    const float4* __restrict__ state, float* __restrict__ out,
    const double* __restrict__ acc,
    const float* __restrict__ g3, const float* __restrict__ b3)
{
    const int b = blockIdx.x * 256 + threadIdx.x;
    const double* a = acc + (size_t)62 * ACC_STRIDE;
    double m3 = a[36] * INV_B;
    double v3 = a[37] * INV_B - m3 * m3; v3 = v3 < 0.0 ? 0.0 : v3;
    double r3 = 1.0 / sqrt(v3 + 1e-6);
    double g  = (double)g3[62], bb = (double)b3[62];
    float z0 = (float)(g * (a[38] - m3) * r3 + bb);
    float z1 = (float)(g * (a[39] - m3) * r3 + bb);

    float dw, s;
    if (TR) { dw = dWt[(size_t)62 * NB + b]; s = St[(size_t)63 * NB + b]; }
    else {
        const float* wr = Wraw + (size_t)b * NT + 62;
        dw = wr[1] - wr[0]; s = Sraw[(size_t)b * NT + 63];
    }
    float4 s4 = state[b];
    float x0 = s4.x, x1 = s4.y, y0 = s4.z, y1 = s4.w;
    float x0n = x0 + (0.05f*s*x0 + 0.01f*s*x1)*DTF + (0.2f*s*x0 + 0.1f*s*x1)*dw;
    float y0n = y0 + RRF*y0*DTF + z0*dw;
    float y1n = y1 + RRF*y1*DTF + z1*(-dw);
    float x1n = x1 - y1n*DTF;
    out[b]          = x0n;
    out[NB + b]     = x1n;
    out[2*NB + b]   = y0n;
    out[3*NB + b]   = y1n;
}

// ---------------- launcher ----------------

extern "C" void kernel_launch(void* const* d_in, const int* in_sizes, int n_in,
                              void* d_out, int out_size, void* d_ws, size_t ws_size,
                              hipStream_t stream)
{
    (void)in_sizes; (void)n_in; (void)out_size;
    char* ws = (char*)d_ws;
    double* acc = (double*)ws;
    unsigned int* fl = (unsigned int*)(ws + FLAG_OFF);
    float* dWt  = (float*)(ws + DWT_OFF);
    float* St   = (float*)(ws + ST_OFF);
    const bool tr = ws_size >= WS_NEED;

    KP p;
    p.Wraw = (const float*)d_in[0];  p.Sraw = (const float*)d_in[1];
    p.dWt = dWt; p.St = St; p.acc = acc; p.fl = fl; p.out = (float*)d_out;
    p.y0i = (const float*)d_in[2];   p.y1i = (const float*)d_in[3];
    p.z0i = (const float*)d_in[4];   p.z1i = (const float*)d_in[5];
    p.g0 = (const float*)d_in[6];    p.b0 = (const float*)d_in[7];
    p.W0 = (const float*)d_in[8];    p.g1 = (const float*)d_in[9];
    p.b1 = (const float*)d_in[10];   p.W1 = (const float*)d_in[11];
    p.g2 = (const float*)d_in[12];   p.b2 = (const float*)d_in[13];
    p.W2 = (const float*)d_in[14];   p.bias2 = (const float*)d_in[15];
    p.g3 = (const float*)d_in[16];   p.b3 = (const float*)d_in[17];

    kinit<<<98, 256, 0, stream>>>(acc);
    if (tr) {
        ktrans<<<NB/64, 256, 0, stream>>>(p.Wraw, dWt, 1);
        ktrans<<<NB/64, 256, 0, stream>>>(p.Sraw, St, 0);
    }

    void (*kfun)(KP) = tr ? kmain<true> : kmain<false>;
    void* args[] = { (void*)&p };
    hipError_t err = hipLaunchCooperativeKernel((const void*)kfun, dim3(BLOCKS),
                                                dim3(TPB), args, 0, stream);
    if (err != hipSuccess) {
        // fallback: proven multi-kernel path (round-2 flat acc layout).
        float4* state;
        float*  h2pre;
        bool fb_tr = tr && ws_size >= (size_t)H2_OFF + (size_t)NB*16 + (size_t)11*NB*4;
        if (fb_tr) {
            state = (float4*)(ws + H2_OFF);
            h2pre = (float*)(ws + H2_OFF + (size_t)NB * 16);
        } else {
            state = (float4*)(ws + DWT_OFF);
            h2pre = (float*)(ws + DWT_OFF + (size_t)NB * 16);
        }
        dim3 grid(NB/256), blk(256);
        for (int t = 0; t < NSTEP; ++t) {
            if (fb_tr) kA<true ><<<grid, blk, 0, stream>>>(p.Wraw, p.Sraw, dWt, St, state, acc, t, p.g3, p.b3, p.y0i, p.y1i, p.z0i, p.z1i);
            else       kA<false><<<grid, blk, 0, stream>>>(p.Wraw, p.Sraw, dWt, St, state, acc, t, p.g3, p.b3, p.y0i, p.y1i, p.z0i, p.z1i);
            kB<<<grid, blk, 0, stream>>>(state, h2pre, acc, t, p.g0, p.b0, p.W0, p.g1, p.b1, p.W1);
            kC<<<grid, blk, 0, stream>>>(h2pre, acc, t, p.g2, p.b2, p.W2, p.bias2);
        }
        if (fb_tr) kF<true ><<<grid, blk, 0, stream>>>(p.Wraw, p.Sraw, dWt, St, state, p.out, acc, p.g3, p.b3);
        else       kF<false><<<grid, blk, 0, stream>>>(p.Wraw, p.Sraw, dWt, St, state, p.out, acc, p.g3, p.b3);
    }
}

// Round 12
// 4338.603 us; speedup vs baseline: 1.0017x; 1.0017x over previous
//
#include <hip/hip_runtime.h>
#include <hip/hip_cooperative_groups.h>

namespace cg = cooperative_groups;

#define NB 262144
#define NT 64
#define NSTEP 63
#define DTF (1.0f/64.0f)
#define DTD (1.0/64.0)
#define RRF 0.05f
#define INV_B (1.0/262144.0)
#define ACC_STRIDE 48
#define NSL 8
#define BLOCKS 256
#define TPB 256
#define PPT 4
#define PSTRIDE (BLOCKS*TPB)   // 65536, 4 paths/thread

// ws layout (bytes)
#define ACC_BYTES   196608                      // 64*8*48 doubles
#define FLAG_OFF    ACC_BYTES
#define FLAG_BYTES  4096                        // 8 arrival ctrs + 8 release words (64B apart)
#define DWT_OFF     (FLAG_OFF + FLAG_BYTES)
#define DWT_BYTES   (63*NB*4)
#define ST_OFF      (DWT_OFF + DWT_BYTES)
#define ST_BYTES    (64*NB*4)
#define H2_OFF      (ST_OFF + ST_BYTES)          // fallback-only scratch
#define WS_NEED     ((size_t)ST_OFF + (size_t)ST_BYTES)

#define ALOADD(p) __hip_atomic_load((double*)(p), __ATOMIC_RELAXED, __HIP_MEMORY_SCOPE_AGENT)

struct KP {
    const float *Wraw, *Sraw, *dWt, *St;
    double* acc; unsigned int* fl; float* out;
    const float *g0,*b0,*W0,*g1,*b1,*W1,*g2,*b2,*W2,*bias2,*g3,*b3;
    const float *y0i,*y1i,*z0i,*z1i;
};

__global__ void kinit(double* __restrict__ z) {
    int i = blockIdx.x * 256 + threadIdx.x;
    if (i < (int)((ACC_BYTES + FLAG_BYTES) / 8)) z[i] = 0.0;
}

__global__ __launch_bounds__(256) void ktrans(const float* __restrict__ in,
                                              float* __restrict__ out, int diffmode) {
    __shared__ float tile[64][65];
    const int b0 = blockIdx.x * 64;
    const int tx = threadIdx.x & 63;
    const int ty = threadIdx.x >> 6;
    #pragma unroll
    for (int i = 0; i < 16; ++i) {
        int p = ty * 16 + i;
        tile[p][tx] = in[(size_t)(b0 + p) * NT + tx];
    }
    __syncthreads();
    if (diffmode) {
        #pragma unroll
        for (int i = 0; i < 16; ++i) {
            int tt = ty * 16 + i;
            if (tt < 63) out[(size_t)tt * NB + b0 + tx] = tile[tx][tt + 1] - tile[tx][tt];
        }
    } else {
        #pragma unroll
        for (int i = 0; i < 16; ++i) {
            int tt = ty * 16 + i;
            out[(size_t)tt * NB + b0 + tx] = tile[tx][tt];
        }
    }
}

// block-level reduce of K doubles, one f64 atomic per value into block's slice.
template<int K>
__device__ __forceinline__ void bred(const double* v, double (*red)[22],
                                     double* target, int tid) {
    const int lane = tid & 63;
    const int wave = tid >> 6;
    #pragma unroll
    for (int k = 0; k < K; ++k) {
        double x = v[k];
        #pragma unroll
        for (int off = 32; off > 0; off >>= 1) x += __shfl_xor(x, off, 64);
        if (lane == 0) red[wave][k] = x;
    }
    __syncthreads();
    if (tid < K) {
        double s = red[0][tid] + red[1][tid] + red[2][tid] + red[3][tid];
        atomicAdd(&target[tid], s);
    }
}

// RMW poll: atomic fetch_add(0) executes at the coherence point ALWAYS —
// a stale local-XCD L2 copy can never satisfy it, unlike a relaxed atomic
// LOAD. This replaces the per-phase acquire-fence (buffer_inv) freshness
// guarantee at zero cache-maintenance cost.
__device__ __forceinline__ unsigned int apoll(unsigned int* p) {
    return __hip_atomic_fetch_add(p, 0u, __ATOMIC_RELAXED,
                                  __HIP_MEMORY_SCOPE_AGENT);
}

// FENCELESS grid barrier, RMW-poll edition.
// All cross-block data flows through coherence-point atomics (f64 atomicAdd
// writes, agent-scope atomic loads), so no cache wb/inv is needed. Arrivals
// spread over 8 padded counters; block 0's leader wave verifies all 8 via
// __all, lanes 0-7 write 8 release copies; other blocks RMW-poll copy
// (bid&7) with s_sleep backoff.
__device__ __forceinline__ void gbar(unsigned int* fl, unsigned int gen) {
    __syncthreads();
    if (threadIdx.x == 0) {
        asm volatile("s_waitcnt vmcnt(0)" ::: "memory");
        __hip_atomic_fetch_add(&fl[(blockIdx.x & 7) * 16], 1u,
                               __ATOMIC_RELAXED, __HIP_MEMORY_SCOPE_AGENT);
    }
    if (blockIdx.x == 0) {
        if (threadIdx.x < 64) {
            for (;;) {
                unsigned int c = apoll(&fl[(threadIdx.x & 7) * 16]);
                if (__all(c >= gen * 32u)) break;
                __builtin_amdgcn_s_sleep(1);
            }
            asm volatile("" ::: "memory");
            if (threadIdx.x < 8)
                __hip_atomic_store(&fl[128 + threadIdx.x * 16], gen,
                                   __ATOMIC_RELAXED, __HIP_MEMORY_SCOPE_AGENT);
        }
    } else if (threadIdx.x == 0) {
        unsigned int* rw = &fl[128 + (blockIdx.x & 7) * 16];
        while (apoll(rw) < gen)
            __builtin_amdgcn_s_sleep(2);
        asm volatile("" ::: "memory");
    }
    __syncthreads();
}

// ================= persistent single-kernel path =================
// 2 barriers/step: phase-A moments are reconstructed analytically from 20
// symbolic sums (state update is affine in z0,z1) reduced during prior C.

template<bool TR>
__global__ __launch_bounds__(256) void kmain(KP p) {
    const int tid = threadIdx.x;
    const int bid = blockIdx.x;
    const int gid = bid * TPB + tid;
    const int sl  = bid & (NSL - 1);
    double* acc = p.acc;
    unsigned int gen = 0;
    #define ACCS(t, q) (acc + ((size_t)(t) * NSL + (q)) * ACC_STRIDE)

    __shared__ float  cf[64];
    __shared__ double red[4][22];
    __shared__ double asum[24];

    float x0[PPT], x1[PPT], y0[PPT], y1[PPT];
    float A0[PPT], A1[PPT], A2[PPT], A3[PPT];
    float dwr[PPT], sr[PPT];
    float h2p[PPT][11];

    // ---------- prologue: step-0 update with z_init + direct 14-moment reduce ----------
    {
        const float z0f = p.z0i[0], z1f = p.z1i[0];
        const float yi0 = p.y0i[0], yi1 = p.y1i[0];
        double v14[14];
        #pragma unroll
        for (int k = 0; k < 14; ++k) v14[k] = 0.0;
        #pragma unroll
        for (int pp = 0; pp < PPT; ++pp) {
            const int pb = gid + pp * PSTRIDE;
            float dw, s;
            if (TR) { dw = p.dWt[pb]; s = p.St[pb]; }
            else {
                const float* wr = p.Wraw + (size_t)pb * NT;
                dw = wr[1] - wr[0]; s = p.Sraw[(size_t)pb * NT];
            }
            dwr[pp] = dw; sr[pp] = s;
            float ox0 = 1.f, ox1 = 0.f, oy0 = yi0, oy1 = yi1;
            float x0n = ox0 + (0.05f*s*ox0 + 0.01f*s*ox1)*DTF
                            + (0.2f*s*ox0 + 0.1f*s*ox1)*dw;
            float y0n = oy0 + RRF*oy0*DTF + z0f*dw;
            float y1n = oy1 + RRF*oy1*DTF + z1f*dw;
            float x1n = ox1 - y1n*DTF;
            x0[pp] = x0n; x1[pp] = x1n; y0[pp] = y0n; y1[pp] = y1n;
            double d0 = x0n, d1 = x1n, d2 = y0n, d3 = y1n;
            v14[0] += d0;    v14[1] += d1;    v14[2] += d2;    v14[3] += d3;
            v14[4] += d0*d0; v14[5] += d0*d1; v14[6] += d0*d2; v14[7] += d0*d3;
            v14[8] += d1*d1; v14[9] += d1*d2; v14[10]+= d1*d3;
            v14[11]+= d2*d2; v14[12]+= d2*d3; v14[13]+= d3*d3;
        }
        bred<14>(v14, red, ACCS(0, sl), tid);
        gbar(p.fl, ++gen);
    }

    #pragma unroll 1
    for (int t = 0; t < NSTEP; ++t) {
        // ---------- phase B: stage sums -> (reconstruct) -> coefs -> h1/h2pre + 22 reduce ----------
        if (t == 0) {
            if (tid < 14) {
                double s = 0.0;
                #pragma unroll
                for (int q = 0; q < NSL; ++q) s += ALOADD(ACCS(0,q) + tid);
                asum[tid] = s;
            }
        } else {
            if (tid < 22) {
                double s = 0.0;
                #pragma unroll
                for (int q = 0; q < NSL; ++q) s += ALOADD(ACCS(t,q) + tid);
                asum[tid] = s;
            } else if (tid == 22) asum[22] = ALOADD(ACCS(t,0) + 44);
            else if   (tid == 23) asum[23] = ALOADD(ACCS(t,0) + 45);
        }
        __syncthreads();
        if (tid < 12) {
            double M1[4], P[10];
            if (t == 0) {
                #pragma unroll
                for (int i = 0; i < 4; ++i) M1[i] = asum[i];
                #pragma unroll
                for (int k = 0; k < 10; ++k) P[k] = asum[4 + k];
            } else {
                double m3 = asum[20] * INV_B;
                double v3 = asum[21] * INV_B - m3 * m3; v3 = v3 < 0.0 ? 0.0 : v3;
                double r3 = 1.0 / sqrt(v3 + 1e-6);
                double g  = (double)p.g3[t-1], bb = (double)p.b3[t-1];
                double z0d = g * (asum[22] - m3) * r3 + bb;
                double z1d = g * (asum[23] - m3) * r3 + bb;
                if (tid == 0) { cf[62] = (float)z0d; cf[63] = (float)z1d; }
                double Sd = asum[18], Sd2 = asum[19];
                M1[0] = asum[0];
                M1[1] = asum[1] - z1d*DTD*Sd;
                M1[2] = asum[2] + z0d*Sd;
                M1[3] = asum[3] + z1d*Sd;
                P[0] = asum[4];
                P[1] = asum[5] - z1d*DTD*asum[14];
                P[2] = asum[6] + z0d*asum[14];
                P[3] = asum[7] + z1d*asum[14];
                P[4] = asum[8] - 2.0*z1d*DTD*asum[15] + z1d*z1d*DTD*DTD*Sd2;
                P[5] = asum[9] + z0d*asum[15] - z1d*DTD*asum[16] - z0d*z1d*DTD*Sd2;
                P[6] = asum[10] + z1d*asum[15] - z1d*DTD*asum[17] - z1d*z1d*DTD*Sd2;
                P[7] = asum[11] + 2.0*z0d*asum[16] + z0d*z0d*Sd2;
                P[8] = asum[12] + z1d*asum[16] + z0d*asum[17] + z0d*z1d*Sd2;
                P[9] = asum[13] + 2.0*z1d*asum[17] + z1d*z1d*Sd2;
            }
            double m[4];
            #pragma unroll
            for (int i = 0; i < 4; ++i) m[i] = M1[i] * INV_B;
            double C[4][4];
            {
                int pidx = 0;
                #pragma unroll
                for (int i = 0; i < 4; ++i)
                    #pragma unroll
                    for (int k = i; k < 4; ++k) {
                        double c = P[pidx++] * INV_B - m[i] * m[k];
                        C[i][k] = c; C[k][i] = c;
                    }
            }
            double u[4];
            #pragma unroll
            for (int i = 0; i < 4; ++i) {
                double vi = C[i][i]; vi = vi < 0.0 ? 0.0 : vi;
                u[i] = (double)p.g0[(size_t)t*4 + i] / sqrt(vi + 1e-6);
            }
            if (tid == 11) {
                #pragma unroll
                for (int i = 0; i < 4; ++i) {
                    cf[0 + i] = (float)u[i];
                    cf[4 + i] = (float)m[i];
                    cf[8 + i] = p.b0[(size_t)t*4 + i];
                }
            } else {
                const int j = tid;
                const float* w0 = p.W0 + (size_t)t * 44;
                double mj = 0.0, vj = 0.0;
                #pragma unroll
                for (int i = 0; i < 4; ++i) {
                    double wij = (double)w0[i*11 + j];
                    mj += (double)p.b0[(size_t)t*4 + i] * wij;
                    double ti = 0.0;
                    #pragma unroll
                    for (int k = 0; k < 4; ++k) ti += u[i]*u[k]*C[i][k]*(double)w0[k*11 + j];
                    vj += wij * ti;
                }
                vj = vj < 0.0 ? 0.0 : vj;
                cf[12 + j] = (float)mj;
                cf[23 + j] = (float)((double)p.g1[(size_t)t*11 + j] / sqrt(vj + 1e-6));
                cf[34 + j] = p.b1[(size_t)t*11 + j];
            }
        }
        __syncthreads();
        if (t > 0) {
            const float zf0 = cf[62], zf1 = cf[63];
            #pragma unroll
            for (int pp = 0; pp < PPT; ++pp) {
                x0[pp] = A0[pp];
                y0[pp] = A2[pp] + zf0 * dwr[pp];
                y1[pp] = A3[pp] + zf1 * dwr[pp];
                x1[pp] = A1[pp] - zf1 * DTF * dwr[pp];
            }
        }
        {
            const float* w0 = p.W0 + (size_t)t * 44;
            const float* w1 = p.W1 + (size_t)t * 121;
            double v22[22];
            #pragma unroll
            for (int k = 0; k < 22; ++k) v22[k] = 0.0;
            #pragma unroll
            for (int pp = 0; pp < PPT; ++pp) {
                float h0[4] = { cf[0]*(x0[pp]-cf[4]) + cf[8],
                                cf[1]*(x1[pp]-cf[5]) + cf[9],
                                cf[2]*(y0[pp]-cf[6]) + cf[10],
                                cf[3]*(y1[pp]-cf[7]) + cf[11] };
                float h1[11];
                #pragma unroll
                for (int j = 0; j < 11; ++j) {
                    float hp = h0[0]*w0[j] + h0[1]*w0[11+j] + h0[2]*w0[22+j] + h0[3]*w0[33+j];
                    h1[j] = fmaxf(cf[23+j]*(hp - cf[12+j]) + cf[34+j], 0.f);
                }
                #pragma unroll
                for (int j = 0; j < 11; ++j) {
                    float hp = 0.f;
                    #pragma unroll
                    for (int i = 0; i < 11; ++i) hp += h1[i] * w1[i*11 + j];
                    h2p[pp][j] = hp;
                    double hd = hp;
                    v22[j] += hd; v22[11+j] += hd*hd;
                }
            }
            bred<22>(v22, red, ACCS(t, sl) + 22, tid);
        }
        gbar(p.fl, ++gen);

        // ---------- phase C: coefs2 -> h3 + symbolic 20 for step t+1 + h3 stats ----------
        if (tid < 22) {
            double s = 0.0;
            #pragma unroll
            for (int q = 0; q < NSL; ++q) s += ALOADD(ACCS(t,q) + 22 + tid);
            asum[tid] = s;
        }
        __syncthreads();
        if (tid < 11) {
            const int j = tid;
            double mj = asum[j] * INV_B;
            double vj = asum[11 + j] * INV_B - mj*mj; vj = vj < 0.0 ? 0.0 : vj;
            cf[j]      = (float)mj;
            cf[11 + j] = (float)((double)p.g2[(size_t)t*11 + j] / sqrt(vj + 1e-6));
            cf[22 + j] = p.b2[(size_t)t*11 + j];
            cf[33 + j] = p.W2[(size_t)t*11 + j];
            if (j == 0) cf[44] = p.bias2[t];
        }
        __syncthreads();
        {
            float h3v[PPT];
            #pragma unroll
            for (int pp = 0; pp < PPT; ++pp) {
                const int pb = gid + pp * PSTRIDE;
                float h3 = cf[44];
                #pragma unroll
                for (int j = 0; j < 11; ++j)
                    h3 += fmaxf(cf[11+j]*(h2p[pp][j] - cf[j]) + cf[22+j], 0.f) * cf[33+j];
                h3v[pp] = h3;
                if (pb == 0) atomicAdd(ACCS(t+1,0) + 44, (double)h3);
                if (pb == 1) atomicAdd(ACCS(t+1,0) + 45, (double)h3);
            }
            if (t < NSTEP - 1) {
                double v22[22];
                #pragma unroll
                for (int k = 0; k < 22; ++k) v22[k] = 0.0;
                #pragma unroll
                for (int pp = 0; pp < PPT; ++pp) {
                    const int pb = gid + pp * PSTRIDE;
                    float dw, s;
                    if (TR) {
                        dw = p.dWt[(size_t)(t+1) * NB + pb];
                        s  = p.St [(size_t)(t+1) * NB + pb];
                    } else {
                        const float* wr = p.Wraw + (size_t)pb * NT + (t+1);
                        dw = wr[1] - wr[0]; s = p.Sraw[(size_t)pb * NT + (t+1)];
                    }
                    dwr[pp] = dw; sr[pp] = s;
                    float a0 = x0[pp] + (0.05f*s*x0[pp] + 0.01f*s*x1[pp])*DTF
                                      + (0.2f*s*x0[pp] + 0.1f*s*x1[pp])*dw;
                    float a2 = y0[pp] + RRF*y0[pp]*DTF;
                    float a3 = y1[pp] + RRF*y1[pp]*DTF;
                    float a1 = x1[pp] - a3*DTF;
                    A0[pp]=a0; A1[pp]=a1; A2[pp]=a2; A3[pp]=a3;
                    double d0=a0, d1=a1, d2=a2, d3=a3, dd=dw;
                    v22[0] += d0;    v22[1] += d1;    v22[2] += d2;    v22[3] += d3;
                    v22[4] += d0*d0; v22[5] += d0*d1; v22[6] += d0*d2; v22[7] += d0*d3;
                    v22[8] += d1*d1; v22[9] += d1*d2; v22[10]+= d1*d3;
                    v22[11]+= d2*d2; v22[12]+= d2*d3; v22[13]+= d3*d3;
                    v22[14]+= d0*dd; v22[15]+= d1*dd; v22[16]+= d2*dd; v22[17]+= d3*dd;
                    v22[18]+= dd;    v22[19]+= dd*dd;
                    double h3d = h3v[pp];
                    v22[20]+= h3d;   v22[21]+= h3d*h3d;
                }
                bred<22>(v22, red, ACCS(t+1, sl), tid);
            } else {
                double v2[2] = {0.0, 0.0};
                #pragma unroll
                for (int pp = 0; pp < PPT; ++pp) {
                    double h3d = h3v[pp];
                    v2[0] += h3d; v2[1] += h3d*h3d;
                }
                bred<2>(v2, red, ACCS(NSTEP, sl) + 20, tid);
            }
        }
        gbar(p.fl, ++gen);
    }

    // ---------- final half-step ----------
    if (tid == 0) {
        double s20 = 0.0, s21 = 0.0;
        #pragma unroll
        for (int q = 0; q < NSL; ++q) {
            s20 += ALOADD(ACCS(NSTEP,q) + 20);
            s21 += ALOADD(ACCS(NSTEP,q) + 21);
        }
        double m3 = s20 * INV_B;
        double v3 = s21 * INV_B - m3*m3; v3 = v3 < 0.0 ? 0.0 : v3;
        double r3 = 1.0 / sqrt(v3 + 1e-6);
        double g = (double)p.g3[62], bb = (double)p.b3[62];
        cf[0] = (float)(g * (ALOADD(ACCS(NSTEP,0) + 44) - m3) * r3 + bb);
        cf[1] = (float)(g * (ALOADD(ACCS(NSTEP,0) + 45) - m3) * r3 + bb);
    }
    __syncthreads();
    {
        const float z0f = cf[0], z1f = cf[1];
        #pragma unroll
        for (int pp = 0; pp < PPT; ++pp) {
            const int pb = gid + pp * PSTRIDE;
            float dw = dwr[pp];   // inputs(62) retained: W[:,63]-W[:,62]
            float s;
            if (TR) s = p.St[(size_t)63 * NB + pb];
            else    s = p.Sraw[(size_t)pb * NT + 63];
            float x0n = x0[pp] + (0.05f*s*x0[pp] + 0.01f*s*x1[pp])*DTF
                               + (0.2f*s*x0[pp] + 0.1f*s*x1[pp])*dw;
            float y0n = y0[pp] + RRF*y0[pp]*DTF + z0f*dw;
            float y1n = y1[pp] + RRF*y1[pp]*DTF + z1f*(-dw);
            float x1n = x1[pp] - y1n*DTF;
            p.out[pb]          = x0n;
            p.out[NB + pb]     = x1n;
            p.out[2*NB + pb]   = y0n;
            p.out[3*NB + pb]   = y1n;
        }
    }
    #undef ACCS
}

// ================= fallback multi-kernel path (round-2, proven) =================

template<bool TR>
__global__ __launch_bounds__(256) void kA(
    const float* __restrict__ Wraw, const float* __restrict__ Sraw,
    const float* __restrict__ dWt,  const float* __restrict__ St,
    float4* __restrict__ state, double* __restrict__ acc, int t,
    const float* __restrict__ g3, const float* __restrict__ b3,
    const float* __restrict__ y0i, const float* __restrict__ y1i,
    const float* __restrict__ z0i, const float* __restrict__ z1i)
{
    __shared__ double red[4][22];
    const int b = blockIdx.x * 256 + threadIdx.x;
    float dw, s;
    if (TR) { dw = dWt[(size_t)t * NB + b]; s = St[(size_t)t * NB + b]; }
    else {
        const float* wr = Wraw + (size_t)b * NT + t;
        dw = wr[1] - wr[0]; s = Sraw[(size_t)b * NT + t];
    }
    float z0, z1, x0, x1, y0, y1;
    if (t == 0) {
        z0 = z0i[0]; z1 = z1i[0];
        x0 = 1.f; x1 = 0.f; y0 = y0i[0]; y1 = y1i[0];
    } else {
        const double* a = acc + (size_t)(t - 1) * ACC_STRIDE;
        double m3 = a[36] * INV_B;
        double v3 = a[37] * INV_B - m3 * m3; v3 = v3 < 0.0 ? 0.0 : v3;
        double r3 = 1.0 / sqrt(v3 + 1e-6);
        double g  = (double)g3[t - 1], bb = (double)b3[t - 1];
        z0 = (float)(g * (a[38] - m3) * r3 + bb);
        z1 = (float)(g * (a[39] - m3) * r3 + bb);
        float4 s4 = state[b];
        x0 = s4.x; x1 = s4.y; y0 = s4.z; y1 = s4.w;
    }
    float x0n = x0 + (0.05f*s*x0 + 0.01f*s*x1)*DTF + (0.2f*s*x0 + 0.1f*s*x1)*dw;
    float y0n = y0 + RRF*y0*DTF + z0*dw;
    float y1n = y1 + RRF*y1*DTF + z1*dw;
    float x1n = x1 - y1n*DTF;
    state[b] = make_float4(x0n, x1n, y0n, y1n);
    double d0 = x0n, d1 = x1n, d2 = y0n, d3 = y1n;
    double v[14] = { d0, d1, d2, d3,
                     d0*d0, d0*d1, d0*d2, d0*d3,
                     d1*d1, d1*d2, d1*d3,
                     d2*d2, d2*d3, d3*d3 };
    bred<14>(v, red, acc + (size_t)t * ACC_STRIDE, threadIdx.x);
}

__global__ __launch_bounds__(256) void kB(
    const float4* __restrict__ state, float* __restrict__ h2pre,
    double* __restrict__ acc, int t,
    const float* __restrict__ g0, const float* __restrict__ b0,
    const float* __restrict__ W0,
    const float* __restrict__ g1, const float* __restrict__ b1,
    const float* __restrict__ W1)
{
    __shared__ double red[4][22];
    const int b = blockIdx.x * 256 + threadIdx.x;
    float4 s4 = state[b];

    const double* a = acc + (size_t)t * ACC_STRIDE;
    double m[4];
    #pragma unroll
    for (int i = 0; i < 4; ++i) m[i] = a[i] * INV_B;
    double C[4][4];
    {
        int p = 4;
        #pragma unroll
        for (int i = 0; i < 4; ++i)
            #pragma unroll
            for (int k = i; k < 4; ++k) {
                double c = a[p++] * INV_B - m[i] * m[k];
                C[i][k] = c; C[k][i] = c;
            }
    }
    const float* w0 = W0 + (size_t)t * 44;
    float w0f[4][11];
    #pragma unroll
    for (int i = 0; i < 4; ++i)
        #pragma unroll
        for (int j = 0; j < 11; ++j) w0f[i][j] = w0[i * 11 + j];

    double u[4]; float uf[4], mf[4], b0f[4];
    #pragma unroll
    for (int i = 0; i < 4; ++i) {
        double vi = C[i][i]; vi = vi < 0.0 ? 0.0 : vi;
        double ri = 1.0 / sqrt(vi + 1e-6);
        u[i]  = (double)g0[(size_t)t * 4 + i] * ri;
        uf[i] = (float)u[i];
        mf[i] = (float)m[i];
        b0f[i] = b0[(size_t)t * 4 + i];
    }
    double M[4][4];
    #pragma unroll
    for (int i = 0; i < 4; ++i)
        #pragma unroll
        for (int k = 0; k < 4; ++k) M[i][k] = u[i] * u[k] * C[i][k];

    float mean1[11], q1[11], b1f[11];
    #pragma unroll
    for (int j = 0; j < 11; ++j) {
        double mj = 0.0, vj = 0.0;
        #pragma unroll
        for (int i = 0; i < 4; ++i) {
            mj += (double)b0f[i] * (double)w0f[i][j];
            double ti = 0.0;
            #pragma unroll
            for (int k = 0; k < 4; ++k) ti += M[i][k] * (double)w0f[k][j];
            vj += (double)w0f[i][j] * ti;
        }
        vj = vj < 0.0 ? 0.0 : vj;
        double rj = 1.0 / sqrt(vj + 1e-6);
        mean1[j] = (float)mj;
        q1[j]    = (float)((double)g1[(size_t)t * 11 + j] * rj);
        b1f[j]   = b1[(size_t)t * 11 + j];
    }

    float h0[4] = { uf[0]*(s4.x - mf[0]) + b0f[0],
                    uf[1]*(s4.y - mf[1]) + b0f[1],
                    uf[2]*(s4.z - mf[2]) + b0f[2],
                    uf[3]*(s4.w - mf[3]) + b0f[3] };
    float h1[11];
    #pragma unroll
    for (int j = 0; j < 11; ++j) {
        float hp = h0[0]*w0f[0][j] + h0[1]*w0f[1][j] + h0[2]*w0f[2][j] + h0[3]*w0f[3][j];
        h1[j] = fmaxf(q1[j] * (hp - mean1[j]) + b1f[j], 0.f);
    }
    const float* w1 = W1 + (size_t)t * 121;
    double v[22];
    #pragma unroll
    for (int j = 0; j < 11; ++j) {
        float hp = 0.f;
        #pragma unroll
        for (int i = 0; i < 11; ++i) hp += h1[i] * w1[i * 11 + j];
        h2pre[(size_t)j * NB + b] = hp;
        double hd = hp;
        v[j] = hd; v[11 + j] = hd * hd;
    }
    bred<22>(v, red, acc + (size_t)t * ACC_STRIDE + 14, threadIdx.x);
}

__global__ __launch_bounds__(256) void kC(
    const float* __restrict__ h2pre, double* __restrict__ acc, int t,
    const float* __restrict__ g2, const float* __restrict__ b2,
    const float* __restrict__ W2, const float* __restrict__ bias2)
{
    __shared__ double red[4][22];
    const int b = blockIdx.x * 256 + threadIdx.x;
    const double* a = acc + (size_t)t * ACC_STRIDE;
    float m2f[11], q2[11], b2f[11], w2f[11];
    #pragma unroll
    for (int j = 0; j < 11; ++j) {
        double mj = a[14 + j] * INV_B;
        double vj = a[25 + j] * INV_B - mj * mj; vj = vj < 0.0 ? 0.0 : vj;
        double rj = 1.0 / sqrt(vj + 1e-6);
        m2f[j] = (float)mj;
        q2[j]  = (float)((double)g2[(size_t)t * 11 + j] * rj);
        b2f[j] = b2[(size_t)t * 11 + j];
        w2f[j] = W2[(size_t)t * 11 + j];
    }
    float h3 = bias2[t];
    #pragma unroll
    for (int j = 0; j < 11; ++j) {
        float hv = h2pre[(size_t)j * NB + b];
        float h2 = fmaxf(q2[j] * (hv - m2f[j]) + b2f[j], 0.f);
        h3 += h2 * w2f[j];
    }
    double* aw = acc + (size_t)t * ACC_STRIDE;
    if (b == 0) aw[38] = (double)h3;
    if (b == 1) aw[39] = (double)h3;
    double hd = h3;
    double v[2] = { hd, hd * hd };
    bred<2>(v, red, aw + 36, threadIdx.x);
}

template<bool TR>
__global__ __launch_bounds__(256) void kF(
    const float* __restrict__ Wraw, const float* __restrict__ Sraw,
    const float* __restrict__ dWt,  const float* __restrict__ St,
    const float4* __restrict__ state, float* __restrict__ out,
    const double* __restrict__ acc,
    const float* __restrict__ g3, const float* __restrict__ b3)
{
    const int b = blockIdx.x * 256 + threadIdx.x;
    const double* a = acc + (size_t)62 * ACC_STRIDE;
    double m3 = a[36] * INV_B;
    double v3 = a[37] * INV_B - m3 * m3; v3 = v3 < 0.0 ? 0.0 : v3;
    double r3 = 1.0 / sqrt(v3 + 1e-6);
    double g  = (double)g3[62], bb = (double)b3[62];
    float z0 = (float)(g * (a[38] - m3) * r3 + bb);
    float z1 = (float)(g * (a[39] - m3) * r3 + bb);

    float dw, s;
    if (TR) { dw = dWt[(size_t)62 * NB + b]; s = St[(size_t)63 * NB + b]; }
    else {
        const float* wr = Wraw + (size_t)b * NT + 62;
        dw = wr[1] - wr[0]; s = Sraw[(size_t)b * NT + 63];
    }
    float4 s4 = state[b];
    float x0 = s4.x, x1 = s4.y, y0 = s4.z, y1 = s4.w;
    float x0n = x0 + (0.05f*s*x0 + 0.01f*s*x1)*DTF + (0.2f*s*x0 + 0.1f*s*x1)*dw;
    float y0n = y0 + RRF*y0*DTF + z0*dw;
    float y1n = y1 + RRF*y1*DTF + z1*(-dw);
    float x1n = x1 - y1n*DTF;
    out[b]          = x0n;
    out[NB + b]     = x1n;
    out[2*NB + b]   = y0n;
    out[3*NB + b]   = y1n;
}

// ---------------- launcher ----------------

extern "C" void kernel_launch(void* const* d_in, const int* in_sizes, int n_in,
                              void* d_out, int out_size, void* d_ws, size_t ws_size,
                              hipStream_t stream)
{
    (void)in_sizes; (void)n_in; (void)out_size;
    char* ws = (char*)d_ws;
    double* acc = (double*)ws;
    unsigned int* fl = (unsigned int*)(ws + FLAG_OFF);
    float* dWt  = (float*)(ws + DWT_OFF);
    float* St   = (float*)(ws + ST_OFF);
    const bool tr = ws_size >= WS_NEED;

    KP p;
    p.Wraw = (const float*)d_in[0];  p.Sraw = (const float*)d_in[1];
    p.dWt = dWt; p.St = St; p.acc = acc; p.fl = fl; p.out = (float*)d_out;
    p.y0i = (const float*)d_in[2];   p.y1i = (const float*)d_in[3];
    p.z0i = (const float*)d_in[4];   p.z1i = (const float*)d_in[5];
    p.g0 = (const float*)d_in[6];    p.b0 = (const float*)d_in[7];
    p.W0 = (const float*)d_in[8];    p.g1 = (const float*)d_in[9];
    p.b1 = (const float*)d_in[10];   p.W1 = (const float*)d_in[11];
    p.g2 = (const float*)d_in[12];   p.b2 = (const float*)d_in[13];
    p.W2 = (const float*)d_in[14];   p.bias2 = (const float*)d_in[15];
    p.g3 = (const float*)d_in[16];   p.b3 = (const float*)d_in[17];

    kinit<<<98, 256, 0, stream>>>(acc);
    if (tr) {
        ktrans<<<NB/64, 256, 0, stream>>>(p.Wraw, dWt, 1);
        ktrans<<<NB/64, 256, 0, stream>>>(p.Sraw, St, 0);
    }

    void (*kfun)(KP) = tr ? kmain<true> : kmain<false>;
    void* args[] = { (void*)&p };
    hipError_t err = hipLaunchCooperativeKernel((const void*)kfun, dim3(BLOCKS),
                                                dim3(TPB), args, 0, stream);
    if (err != hipSuccess) {
        // fallback: proven multi-kernel path (round-2 flat acc layout).
        float4* state;
        float*  h2pre;
        bool fb_tr = tr && ws_size >= (size_t)H2_OFF + (size_t)NB*16 + (size_t)11*NB*4;
        if (fb_tr) {
            state = (float4*)(ws + H2_OFF);
            h2pre = (float*)(ws + H2_OFF + (size_t)NB * 16);
        } else {
            state = (float4*)(ws + DWT_OFF);
            h2pre = (float*)(ws + DWT_OFF + (size_t)NB * 16);
        }
        dim3 grid(NB/256), blk(256);
        for (int t = 0; t < NSTEP; ++t) {
            if (fb_tr) kA<true ><<<grid, blk, 0, stream>>>(p.Wraw, p.Sraw, dWt, St, state, acc, t, p.g3, p.b3, p.y0i, p.y1i, p.z0i, p.z1i);
            else       kA<false><<<grid, blk, 0, stream>>>(p.Wraw, p.Sraw, dWt, St, state, acc, t, p.g3, p.b3, p.y0i, p.y1i, p.z0i, p.z1i);
            kB<<<grid, blk, 0, stream>>>(state, h2pre, acc, t, p.g0, p.b0, p.W0, p.g1, p.b1, p.W1);
            kC<<<grid, blk, 0, stream>>>(h2pre, acc, t, p.g2, p.b2, p.W2, p.bias2);
        }
        if (fb_tr) kF<true ><<<grid, blk, 0, stream>>>(p.Wraw, p.Sraw, dWt, St, state, p.out, acc, p.g3, p.b3);
        else       kF<false><<<grid, blk, 0, stream>>>(p.Wraw, p.Sraw, dWt, St, state, p.out, acc, p.g3, p.b3);
    }
}

// Round 13
// 1503.535 us; speedup vs baseline: 2.8905x; 2.8856x over previous
//
#include <hip/hip_runtime.h>
#include <hip/hip_cooperative_groups.h>

namespace cg = cooperative_groups;

#define NB 262144
#define NT 64
#define NSTEP 63
#define DTF (1.0f/64.0f)
#define DTD (1.0/64.0)
#define RRF 0.05f
#define INV_B (1.0/262144.0)
#define ACC_STRIDE 48
#define NSL 8
#define BLOCKS 256
#define TPB 256
#define PPT 4
#define PSTRIDE (BLOCKS*TPB)   // 65536, 4 paths/thread

// ws layout (bytes)
#define ACC_BYTES   196608                      // 64*8*48 doubles
#define FLAG_OFF    ACC_BYTES
#define FLAG_BYTES  4096                        // 8 arrival ctrs + 8 release words (64B apart)
#define DWT_OFF     (FLAG_OFF + FLAG_BYTES)
#define DWT_BYTES   (63*NB*4)
#define ST_OFF      (DWT_OFF + DWT_BYTES)
#define ST_BYTES    (64*NB*4)
#define H2_OFF      (ST_OFF + ST_BYTES)          // fallback-only scratch
#define WS_NEED     ((size_t)ST_OFF + (size_t)ST_BYTES)

#define ALOADD(p) __hip_atomic_load((double*)(p), __ATOMIC_RELAXED, __HIP_MEMORY_SCOPE_AGENT)

struct KP {
    const float *Wraw, *Sraw, *dWt, *St;
    double* acc; unsigned int* fl; float* out;
    const float *g0,*b0,*W0,*g1,*b1,*W1,*g2,*b2,*W2,*bias2,*g3,*b3;
    const float *y0i,*y1i,*z0i,*z1i;
};

__global__ void kinit(double* __restrict__ z) {
    int i = blockIdx.x * 256 + threadIdx.x;
    if (i < (int)((ACC_BYTES + FLAG_BYTES) / 8)) z[i] = 0.0;
}

__global__ __launch_bounds__(256) void ktrans(const float* __restrict__ in,
                                              float* __restrict__ out, int diffmode) {
    __shared__ float tile[64][65];
    const int b0 = blockIdx.x * 64;
    const int tx = threadIdx.x & 63;
    const int ty = threadIdx.x >> 6;
    #pragma unroll
    for (int i = 0; i < 16; ++i) {
        int p = ty * 16 + i;
        tile[p][tx] = in[(size_t)(b0 + p) * NT + tx];
    }
    __syncthreads();
    if (diffmode) {
        #pragma unroll
        for (int i = 0; i < 16; ++i) {
            int tt = ty * 16 + i;
            if (tt < 63) out[(size_t)tt * NB + b0 + tx] = tile[tx][tt + 1] - tile[tx][tt];
        }
    } else {
        #pragma unroll
        for (int i = 0; i < 16; ++i) {
            int tt = ty * 16 + i;
            out[(size_t)tt * NB + b0 + tx] = tile[tx][tt];
        }
    }
}

// block-level reduce of K doubles, one f64 atomic per value into block's slice.
template<int K>
__device__ __forceinline__ void bred(const double* v, double (*red)[22],
                                     double* target, int tid) {
    const int lane = tid & 63;
    const int wave = tid >> 6;
    #pragma unroll
    for (int k = 0; k < K; ++k) {
        double x = v[k];
        #pragma unroll
        for (int off = 32; off > 0; off >>= 1) x += __shfl_xor(x, off, 64);
        if (lane == 0) red[wave][k] = x;
    }
    __syncthreads();
    if (tid < K) {
        double s = red[0][tid] + red[1][tid] + red[2][tid] + red[3][tid];
        atomicAdd(&target[tid], s);
    }
}

// Grid barrier, RELEASE-FENCE-ONLY edition (A/B vs round 9's both-fences).
//  - arrival: release fence (wbl2) + RMW increment — orders data atomics,
//    harness-consistency candidate (r9 had it; fenceless r10-12 did not).
//  - NO acquire fence (buffer_inv) anywhere: agent-scope atomic reads
//    (ALOADD/polls) bypass stale cache copies by construction — proven by
//    r10-12 passing validation. Dropping inv keeps weights L2-resident.
__device__ __forceinline__ void gbar(unsigned int* fl, unsigned int gen) {
    __syncthreads();
    if (threadIdx.x == 0) {
        __builtin_amdgcn_fence(__ATOMIC_RELEASE, "agent");
        __hip_atomic_fetch_add(&fl[(blockIdx.x & 7) * 16], 1u,
                               __ATOMIC_RELAXED, __HIP_MEMORY_SCOPE_AGENT);
    }
    if (blockIdx.x == 0) {
        if (threadIdx.x < 64) {
            for (;;) {
                unsigned int c = __hip_atomic_load(&fl[(threadIdx.x & 7) * 16],
                    __ATOMIC_RELAXED, __HIP_MEMORY_SCOPE_AGENT);
                if (__all(c >= gen * 32u)) break;
                __builtin_amdgcn_s_sleep(1);
            }
            asm volatile("" ::: "memory");
            if (threadIdx.x < 8) {
                __builtin_amdgcn_fence(__ATOMIC_RELEASE, "agent");
                __hip_atomic_store(&fl[128 + threadIdx.x * 16], gen,
                                   __ATOMIC_RELAXED, __HIP_MEMORY_SCOPE_AGENT);
            }
        }
    } else if (threadIdx.x == 0) {
        const int rw = 128 + (blockIdx.x & 7) * 16;
        while (__hip_atomic_load(&fl[rw], __ATOMIC_RELAXED,
                                 __HIP_MEMORY_SCOPE_AGENT) < gen)
            __builtin_amdgcn_s_sleep(2);
        asm volatile("" ::: "memory");
    }
    __syncthreads();
}

// ================= persistent single-kernel path =================
// 2 barriers/step: phase-A moments are reconstructed analytically from 20
// symbolic sums (state update is affine in z0,z1) reduced during prior C.

template<bool TR>
__global__ __launch_bounds__(256) void kmain(KP p) {
    const int tid = threadIdx.x;
    const int bid = blockIdx.x;
    const int gid = bid * TPB + tid;
    const int sl  = bid & (NSL - 1);
    double* acc = p.acc;
    unsigned int gen = 0;
    #define ACCS(t, q) (acc + ((size_t)(t) * NSL + (q)) * ACC_STRIDE)

    __shared__ float  cf[64];
    __shared__ double red[4][22];
    __shared__ double asum[24];

    float x0[PPT], x1[PPT], y0[PPT], y1[PPT];
    float A0[PPT], A1[PPT], A2[PPT], A3[PPT];
    float dwr[PPT], sr[PPT];
    float h2p[PPT][11];

    // ---------- prologue: step-0 update with z_init + direct 14-moment reduce ----------
    {
        const float z0f = p.z0i[0], z1f = p.z1i[0];
        const float yi0 = p.y0i[0], yi1 = p.y1i[0];
        double v14[14];
        #pragma unroll
        for (int k = 0; k < 14; ++k) v14[k] = 0.0;
        #pragma unroll
        for (int pp = 0; pp < PPT; ++pp) {
            const int pb = gid + pp * PSTRIDE;
            float dw, s;
            if (TR) { dw = p.dWt[pb]; s = p.St[pb]; }
            else {
                const float* wr = p.Wraw + (size_t)pb * NT;
                dw = wr[1] - wr[0]; s = p.Sraw[(size_t)pb * NT];
            }
            dwr[pp] = dw; sr[pp] = s;
            float ox0 = 1.f, ox1 = 0.f, oy0 = yi0, oy1 = yi1;
            float x0n = ox0 + (0.05f*s*ox0 + 0.01f*s*ox1)*DTF
                            + (0.2f*s*ox0 + 0.1f*s*ox1)*dw;
            float y0n = oy0 + RRF*oy0*DTF + z0f*dw;
            float y1n = oy1 + RRF*oy1*DTF + z1f*dw;
            float x1n = ox1 - y1n*DTF;
            x0[pp] = x0n; x1[pp] = x1n; y0[pp] = y0n; y1[pp] = y1n;
            double d0 = x0n, d1 = x1n, d2 = y0n, d3 = y1n;
            v14[0] += d0;    v14[1] += d1;    v14[2] += d2;    v14[3] += d3;
            v14[4] += d0*d0; v14[5] += d0*d1; v14[6] += d0*d2; v14[7] += d0*d3;
            v14[8] += d1*d1; v14[9] += d1*d2; v14[10]+= d1*d3;
            v14[11]+= d2*d2; v14[12]+= d2*d3; v14[13]+= d3*d3;
        }
        bred<14>(v14, red, ACCS(0, sl), tid);
        gbar(p.fl, ++gen);
    }

    #pragma unroll 1
    for (int t = 0; t < NSTEP; ++t) {
        // ---------- phase B: stage sums -> (reconstruct) -> coefs -> h1/h2pre + 22 reduce ----------
        if (t == 0) {
            if (tid < 14) {
                double s = 0.0;
                #pragma unroll
                for (int q = 0; q < NSL; ++q) s += ALOADD(ACCS(0,q) + tid);
                asum[tid] = s;
            }
        } else {
            if (tid < 22) {
                double s = 0.0;
                #pragma unroll
                for (int q = 0; q < NSL; ++q) s += ALOADD(ACCS(t,q) + tid);
                asum[tid] = s;
            } else if (tid == 22) asum[22] = ALOADD(ACCS(t,0) + 44);
            else if   (tid == 23) asum[23] = ALOADD(ACCS(t,0) + 45);
        }
        __syncthreads();
        if (tid < 12) {
            double M1[4], P[10];
            if (t == 0) {
                #pragma unroll
                for (int i = 0; i < 4; ++i) M1[i] = asum[i];
                #pragma unroll
                for (int k = 0; k < 10; ++k) P[k] = asum[4 + k];
            } else {
                double m3 = asum[20] * INV_B;
                double v3 = asum[21] * INV_B - m3 * m3; v3 = v3 < 0.0 ? 0.0 : v3;
                double r3 = 1.0 / sqrt(v3 + 1e-6);
                double g  = (double)p.g3[t-1], bb = (double)p.b3[t-1];
                double z0d = g * (asum[22] - m3) * r3 + bb;
                double z1d = g * (asum[23] - m3) * r3 + bb;
                if (tid == 0) { cf[62] = (float)z0d; cf[63] = (float)z1d; }
                double Sd = asum[18], Sd2 = asum[19];
                M1[0] = asum[0];
                M1[1] = asum[1] - z1d*DTD*Sd;
                M1[2] = asum[2] + z0d*Sd;
                M1[3] = asum[3] + z1d*Sd;
                P[0] = asum[4];
                P[1] = asum[5] - z1d*DTD*asum[14];
                P[2] = asum[6] + z0d*asum[14];
                P[3] = asum[7] + z1d*asum[14];
                P[4] = asum[8] - 2.0*z1d*DTD*asum[15] + z1d*z1d*DTD*DTD*Sd2;
                P[5] = asum[9] + z0d*asum[15] - z1d*DTD*asum[16] - z0d*z1d*DTD*Sd2;
                P[6] = asum[10] + z1d*asum[15] - z1d*DTD*asum[17] - z1d*z1d*DTD*Sd2;
                P[7] = asum[11] + 2.0*z0d*asum[16] + z0d*z0d*Sd2;
                P[8] = asum[12] + z1d*asum[16] + z0d*asum[17] + z0d*z1d*Sd2;
                P[9] = asum[13] + 2.0*z1d*asum[17] + z1d*z1d*Sd2;
            }
            double m[4];
            #pragma unroll
            for (int i = 0; i < 4; ++i) m[i] = M1[i] * INV_B;
            double C[4][4];
            {
                int pidx = 0;
                #pragma unroll
                for (int i = 0; i < 4; ++i)
                    #pragma unroll
                    for (int k = i; k < 4; ++k) {
                        double c = P[pidx++] * INV_B - m[i] * m[k];
                        C[i][k] = c; C[k][i] = c;
                    }
            }
            double u[4];
            #pragma unroll
            for (int i = 0; i < 4; ++i) {
                double vi = C[i][i]; vi = vi < 0.0 ? 0.0 : vi;
                u[i] = (double)p.g0[(size_t)t*4 + i] / sqrt(vi + 1e-6);
            }
            if (tid == 11) {
                #pragma unroll
                for (int i = 0; i < 4; ++i) {
                    cf[0 + i] = (float)u[i];
                    cf[4 + i] = (float)m[i];
                    cf[8 + i] = p.b0[(size_t)t*4 + i];
                }
            } else {
                const int j = tid;
                const float* w0 = p.W0 + (size_t)t * 44;
                double mj = 0.0, vj = 0.0;
                #pragma unroll
                for (int i = 0; i < 4; ++i) {
                    double wij = (double)w0[i*11 + j];
                    mj += (double)p.b0[(size_t)t*4 + i] * wij;
                    double ti = 0.0;
                    #pragma unroll
                    for (int k = 0; k < 4; ++k) ti += u[i]*u[k]*C[i][k]*(double)w0[k*11 + j];
                    vj += wij * ti;
                }
                vj = vj < 0.0 ? 0.0 : vj;
                cf[12 + j] = (float)mj;
                cf[23 + j] = (float)((double)p.g1[(size_t)t*11 + j] / sqrt(vj + 1e-6));
                cf[34 + j] = p.b1[(size_t)t*11 + j];
            }
        }
        __syncthreads();
        if (t > 0) {
            const float zf0 = cf[62], zf1 = cf[63];
            #pragma unroll
            for (int pp = 0; pp < PPT; ++pp) {
                x0[pp] = A0[pp];
                y0[pp] = A2[pp] + zf0 * dwr[pp];
                y1[pp] = A3[pp] + zf1 * dwr[pp];
                x1[pp] = A1[pp] - zf1 * DTF * dwr[pp];
            }
        }
        {
            const float* w0 = p.W0 + (size_t)t * 44;
            const float* w1 = p.W1 + (size_t)t * 121;
            double v22[22];
            #pragma unroll
            for (int k = 0; k < 22; ++k) v22[k] = 0.0;
            #pragma unroll
            for (int pp = 0; pp < PPT; ++pp) {
                float h0[4] = { cf[0]*(x0[pp]-cf[4]) + cf[8],
                                cf[1]*(x1[pp]-cf[5]) + cf[9],
                                cf[2]*(y0[pp]-cf[6]) + cf[10],
                                cf[3]*(y1[pp]-cf[7]) + cf[11] };
                float h1[11];
                #pragma unroll
                for (int j = 0; j < 11; ++j) {
                    float hp = h0[0]*w0[j] + h0[1]*w0[11+j] + h0[2]*w0[22+j] + h0[3]*w0[33+j];
                    h1[j] = fmaxf(cf[23+j]*(hp - cf[12+j]) + cf[34+j], 0.f);
                }
                #pragma unroll
                for (int j = 0; j < 11; ++j) {
                    float hp = 0.f;
                    #pragma unroll
                    for (int i = 0; i < 11; ++i) hp += h1[i] * w1[i*11 + j];
                    h2p[pp][j] = hp;
                    double hd = hp;
                    v22[j] += hd; v22[11+j] += hd*hd;
                }
            }
            bred<22>(v22, red, ACCS(t, sl) + 22, tid);
        }
        gbar(p.fl, ++gen);

        // ---------- phase C: coefs2 -> h3 + symbolic 20 for step t+1 + h3 stats ----------
        if (tid < 22) {
            double s = 0.0;
            #pragma unroll
            for (int q = 0; q < NSL; ++q) s += ALOADD(ACCS(t,q) + 22 + tid);
            asum[tid] = s;
        }
        __syncthreads();
        if (tid < 11) {
            const int j = tid;
            double mj = asum[j] * INV_B;
            double vj = asum[11 + j] * INV_B - mj*mj; vj = vj < 0.0 ? 0.0 : vj;
            cf[j]      = (float)mj;
            cf[11 + j] = (float)((double)p.g2[(size_t)t*11 + j] / sqrt(vj + 1e-6));
            cf[22 + j] = p.b2[(size_t)t*11 + j];
            cf[33 + j] = p.W2[(size_t)t*11 + j];
            if (j == 0) cf[44] = p.bias2[t];
        }
        __syncthreads();
        {
            float h3v[PPT];
            #pragma unroll
            for (int pp = 0; pp < PPT; ++pp) {
                const int pb = gid + pp * PSTRIDE;
                float h3 = cf[44];
                #pragma unroll
                for (int j = 0; j < 11; ++j)
                    h3 += fmaxf(cf[11+j]*(h2p[pp][j] - cf[j]) + cf[22+j], 0.f) * cf[33+j];
                h3v[pp] = h3;
                if (pb == 0) atomicAdd(ACCS(t+1,0) + 44, (double)h3);
                if (pb == 1) atomicAdd(ACCS(t+1,0) + 45, (double)h3);
            }
            if (t < NSTEP - 1) {
                double v22[22];
                #pragma unroll
                for (int k = 0; k < 22; ++k) v22[k] = 0.0;
                #pragma unroll
                for (int pp = 0; pp < PPT; ++pp) {
                    const int pb = gid + pp * PSTRIDE;
                    float dw, s;
                    if (TR) {
                        dw = p.dWt[(size_t)(t+1) * NB + pb];
                        s  = p.St [(size_t)(t+1) * NB + pb];
                    } else {
                        const float* wr = p.Wraw + (size_t)pb * NT + (t+1);
                        dw = wr[1] - wr[0]; s = p.Sraw[(size_t)pb * NT + (t+1)];
                    }
                    dwr[pp] = dw; sr[pp] = s;
                    float a0 = x0[pp] + (0.05f*s*x0[pp] + 0.01f*s*x1[pp])*DTF
                                      + (0.2f*s*x0[pp] + 0.1f*s*x1[pp])*dw;
                    float a2 = y0[pp] + RRF*y0[pp]*DTF;
                    float a3 = y1[pp] + RRF*y1[pp]*DTF;
                    float a1 = x1[pp] - a3*DTF;
                    A0[pp]=a0; A1[pp]=a1; A2[pp]=a2; A3[pp]=a3;
                    double d0=a0, d1=a1, d2=a2, d3=a3, dd=dw;
                    v22[0] += d0;    v22[1] += d1;    v22[2] += d2;    v22[3] += d3;
                    v22[4] += d0*d0; v22[5] += d0*d1; v22[6] += d0*d2; v22[7] += d0*d3;
                    v22[8] += d1*d1; v22[9] += d1*d2; v22[10]+= d1*d3;
                    v22[11]+= d2*d2; v22[12]+= d2*d3; v22[13]+= d3*d3;
                    v22[14]+= d0*dd; v22[15]+= d1*dd; v22[16]+= d2*dd; v22[17]+= d3*dd;
                    v22[18]+= dd;    v22[19]+= dd*dd;
                    double h3d = h3v[pp];
                    v22[20]+= h3d;   v22[21]+= h3d*h3d;
                }
                bred<22>(v22, red, ACCS(t+1, sl), tid);
            } else {
                double v2[2] = {0.0, 0.0};
                #pragma unroll
                for (int pp = 0; pp < PPT; ++pp) {
                    double h3d = h3v[pp];
                    v2[0] += h3d; v2[1] += h3d*h3d;
                }
                bred<2>(v2, red, ACCS(NSTEP, sl) + 20, tid);
            }
        }
        gbar(p.fl, ++gen);
    }

    // ---------- final half-step ----------
    if (tid == 0) {
        double s20 = 0.0, s21 = 0.0;
        #pragma unroll
        for (int q = 0; q < NSL; ++q) {
            s20 += ALOADD(ACCS(NSTEP,q) + 20);
            s21 += ALOADD(ACCS(NSTEP,q) + 21);
        }
        double m3 = s20 * INV_B;
        double v3 = s21 * INV_B - m3*m3; v3 = v3 < 0.0 ? 0.0 : v3;
        double r3 = 1.0 / sqrt(v3 + 1e-6);
        double g = (double)p.g3[62], bb = (double)p.b3[62];
        cf[0] = (float)(g * (ALOADD(ACCS(NSTEP,0) + 44) - m3) * r3 + bb);
        cf[1] = (float)(g * (ALOADD(ACCS(NSTEP,0) + 45) - m3) * r3 + bb);
    }
    __syncthreads();
    {
        const float z0f = cf[0], z1f = cf[1];
        #pragma unroll
        for (int pp = 0; pp < PPT; ++pp) {
            const int pb = gid + pp * PSTRIDE;
            float dw = dwr[pp];   // inputs(62) retained: W[:,63]-W[:,62]
            float s;
            if (TR) s = p.St[(size_t)63 * NB + pb];
            else    s = p.Sraw[(size_t)pb * NT + 63];
            float x0n = x0[pp] + (0.05f*s*x0[pp] + 0.01f*s*x1[pp])*DTF
                               + (0.2f*s*x0[pp] + 0.1f*s*x1[pp])*dw;
            float y0n = y0[pp] + RRF*y0[pp]*DTF + z0f*dw;
            float y1n = y1[pp] + RRF*y1[pp]*DTF + z1f*(-dw);
            float x1n = x1[pp] - y1n*DTF;
            p.out[pb]          = x0n;
            p.out[NB + pb]     = x1n;
            p.out[2*NB + pb]   = y0n;
            p.out[3*NB + pb]   = y1n;
        }
    }
    #undef ACCS
}

// ================= fallback multi-kernel path (round-2, proven) =================

template<bool TR>
__global__ __launch_bounds__(256) void kA(
    const float* __restrict__ Wraw, const float* __restrict__ Sraw,
    const float* __restrict__ dWt,  const float* __restrict__ St,
    float4* __restrict__ state, double* __restrict__ acc, int t,
    const float* __restrict__ g3, const float* __restrict__ b3,
    const float* __restrict__ y0i, const float* __restrict__ y1i,
    const float* __restrict__ z0i, const float* __restrict__ z1i)
{
    __shared__ double red[4][22];
    const int b = blockIdx.x * 256 + threadIdx.x;
    float dw, s;
    if (TR) { dw = dWt[(size_t)t * NB + b]; s = St[(size_t)t * NB + b]; }
    else {
        const float* wr = Wraw + (size_t)b * NT + t;
        dw = wr[1] - wr[0]; s = Sraw[(size_t)b * NT + t];
    }
    float z0, z1, x0, x1, y0, y1;
    if (t == 0) {
        z0 = z0i[0]; z1 = z1i[0];
        x0 = 1.f; x1 = 0.f; y0 = y0i[0]; y1 = y1i[0];
    } else {
        const double* a = acc + (size_t)(t - 1) * ACC_STRIDE;
        double m3 = a[36] * INV_B;
        double v3 = a[37] * INV_B - m3 * m3; v3 = v3 < 0.0 ? 0.0 : v3;
        double r3 = 1.0 / sqrt(v3 + 1e-6);
        double g  = (double)g3[t - 1], bb = (double)b3[t - 1];
        z0 = (float)(g * (a[38] - m3) * r3 + bb);
        z1 = (float)(g * (a[39] - m3) * r3 + bb);
        float4 s4 = state[b];
        x0 = s4.x; x1 = s4.y; y0 = s4.z; y1 = s4.w;
    }
    float x0n = x0 + (0.05f*s*x0 + 0.01f*s*x1)*DTF + (0.2f*s*x0 + 0.1f*s*x1)*dw;
    float y0n = y0 + RRF*y0*DTF + z0*dw;
    float y1n = y1 + RRF*y1*DTF + z1*dw;
    float x1n = x1 - y1n*DTF;
    state[b] = make_float4(x0n, x1n, y0n, y1n);
    double d0 = x0n, d1 = x1n, d2 = y0n, d3 = y1n;
    double v[14] = { d0, d1, d2, d3,
                     d0*d0, d0*d1, d0*d2, d0*d3,
                     d1*d1, d1*d2, d1*d3,
                     d2*d2, d2*d3, d3*d3 };
    bred<14>(v, red, acc + (size_t)t * ACC_STRIDE, threadIdx.x);
}

__global__ __launch_bounds__(256) void kB(
    const float4* __restrict__ state, float* __restrict__ h2pre,
    double* __restrict__ acc, int t,
    const float* __restrict__ g0, const float* __restrict__ b0,
    const float* __restrict__ W0,
    const float* __restrict__ g1, const float* __restrict__ b1,
    const float* __restrict__ W1)
{
    __shared__ double red[4][22];
    const int b = blockIdx.x * 256 + threadIdx.x;
    float4 s4 = state[b];

    const double* a = acc + (size_t)t * ACC_STRIDE;
    double m[4];
    #pragma unroll
    for (int i = 0; i < 4; ++i) m[i] = a[i] * INV_B;
    double C[4][4];
    {
        int p = 4;
        #pragma unroll
        for (int i = 0; i < 4; ++i)
            #pragma unroll
            for (int k = i; k < 4; ++k) {
                double c = a[p++] * INV_B - m[i] * m[k];
                C[i][k] = c; C[k][i] = c;
            }
    }
    const float* w0 = W0 + (size_t)t * 44;
    float w0f[4][11];
    #pragma unroll
    for (int i = 0; i < 4; ++i)
        #pragma unroll
        for (int j = 0; j < 11; ++j) w0f[i][j] = w0[i * 11 + j];

    double u[4]; float uf[4], mf[4], b0f[4];
    #pragma unroll
    for (int i = 0; i < 4; ++i) {
        double vi = C[i][i]; vi = vi < 0.0 ? 0.0 : vi;
        double ri = 1.0 / sqrt(vi + 1e-6);
        u[i]  = (double)g0[(size_t)t * 4 + i] * ri;
        uf[i] = (float)u[i];
        mf[i] = (float)m[i];
        b0f[i] = b0[(size_t)t * 4 + i];
    }
    double M[4][4];
    #pragma unroll
    for (int i = 0; i < 4; ++i)
        #pragma unroll
        for (int k = 0; k < 4; ++k) M[i][k] = u[i] * u[k] * C[i][k];

    float mean1[11], q1[11], b1f[11];
    #pragma unroll
    for (int j = 0; j < 11; ++j) {
        double mj = 0.0, vj = 0.0;
        #pragma unroll
        for (int i = 0; i < 4; ++i) {
            mj += (double)b0f[i] * (double)w0f[i][j];
            double ti = 0.0;
            #pragma unroll
            for (int k = 0; k < 4; ++k) ti += M[i][k] * (double)w0f[k][j];
            vj += (double)w0f[i][j] * ti;
        }
        vj = vj < 0.0 ? 0.0 : vj;
        double rj = 1.0 / sqrt(vj + 1e-6);
        mean1[j] = (float)mj;
        q1[j]    = (float)((double)g1[(size_t)t * 11 + j] * rj);
        b1f[j]   = b1[(size_t)t * 11 + j];
    }

    float h0[4] = { uf[0]*(s4.x - mf[0]) + b0f[0],
                    uf[1]*(s4.y - mf[1]) + b0f[1],
                    uf[2]*(s4.z - mf[2]) + b0f[2],
                    uf[3]*(s4.w - mf[3]) + b0f[3] };
    float h1[11];
    #pragma unroll
    for (int j = 0; j < 11; ++j) {
        float hp = h0[0]*w0f[0][j] + h0[1]*w0f[1][j] + h0[2]*w0f[2][j] + h0[3]*w0f[3][j];
        h1[j] = fmaxf(q1[j] * (hp - mean1[j]) + b1f[j], 0.f);
    }
    const float* w1 = W1 + (size_t)t * 121;
    double v[22];
    #pragma unroll
    for (int j = 0; j < 11; ++j) {
        float hp = 0.f;
        #pragma unroll
        for (int i = 0; i < 11; ++i) hp += h1[i] * w1[i * 11 + j];
        h2pre[(size_t)j * NB + b] = hp;
        double hd = hp;
        v[j] = hd; v[11 + j] = hd * hd;
    }
    bred<22>(v, red, acc + (size_t)t * ACC_STRIDE + 14, threadIdx.x);
}

__global__ __launch_bounds__(256) void kC(
    const float* __restrict__ h2pre, double* __restrict__ acc, int t,
    const float* __restrict__ g2, const float* __restrict__ b2,
    const float* __restrict__ W2, const float* __restrict__ bias2)
{
    __shared__ double red[4][22];
    const int b = blockIdx.x * 256 + threadIdx.x;
    const double* a = acc + (size_t)t * ACC_STRIDE;
    float m2f[11], q2[11], b2f[11], w2f[11];
    #pragma unroll
    for (int j = 0; j < 11; ++j) {
        double mj = a[14 + j] * INV_B;
        double vj = a[25 + j] * INV_B - mj * mj; vj = vj < 0.0 ? 0.0 : vj;
        double rj = 1.0 / sqrt(vj + 1e-6);
        m2f[j] = (float)mj;
        q2[j]  = (float)((double)g2[(size_t)t * 11 + j] * rj);
        b2f[j] = b2[(size_t)t * 11 + j];
        w2f[j] = W2[(size_t)t * 11 + j];
    }
    float h3 = bias2[t];
    #pragma unroll
    for (int j = 0; j < 11; ++j) {
        float hv = h2pre[(size_t)j * NB + b];
        float h2 = fmaxf(q2[j] * (hv - m2f[j]) + b2f[j], 0.f);
        h3 += h2 * w2f[j];
    }
    double* aw = acc + (size_t)t * ACC_STRIDE;
    if (b == 0) aw[38] = (double)h3;
    if (b == 1) aw[39] = (double)h3;
    double hd = h3;
    double v[2] = { hd, hd * hd };
    bred<2>(v, red, aw + 36, threadIdx.x);
}

template<bool TR>
__global__ __launch_bounds__(256) void kF(
    const float* __restrict__ Wraw, const float* __restrict__ Sraw,
    const float* __restrict__ dWt,  const float* __restrict__ St,
    const float4* __restrict__ state, float* __restrict__ out,
    const double* __restrict__ acc,
    const float* __restrict__ g3, const float* __restrict__ b3)
{
    const int b = blockIdx.x * 256 + threadIdx.x;
    const double* a = acc + (size_t)62 * ACC_STRIDE;
    double m3 = a[36] * INV_B;
    double v3 = a[37] * INV_B - m3 * m3; v3 = v3 < 0.0 ? 0.0 : v3;
    double r3 = 1.0 / sqrt(v3 + 1e-6);
    double g  = (double)g3[62], bb = (double)b3[62];
    float z0 = (float)(g * (a[38] - m3) * r3 + bb);
    float z1 = (float)(g * (a[39] - m3) * r3 + bb);

    float dw, s;
    if (TR) { dw = dWt[(size_t)62 * NB + b]; s = St[(size_t)63 * NB + b]; }
    else {
        const float* wr = Wraw + (size_t)b * NT + 62;
        dw = wr[1] - wr[0]; s = Sraw[(size_t)b * NT + 63];
    }
    float4 s4 = state[b];
    float x0 = s4.x, x1 = s4.y, y0 = s4.z, y1 = s4.w;
    float x0n = x0 + (0.05f*s*x0 + 0.01f*s*x1)*DTF + (0.2f*s*x0 + 0.1f*s*x1)*dw;
    float y0n = y0 + RRF*y0*DTF + z0*dw;
    float y1n = y1 + RRF*y1*DTF + z1*(-dw);
    float x1n = x1 - y1n*DTF;
    out[b]          = x0n;
    out[NB + b]     = x1n;
    out[2*NB + b]   = y0n;
    out[3*NB + b]   = y1n;
}

// ---------------- launcher ----------------

extern "C" void kernel_launch(void* const* d_in, const int* in_sizes, int n_in,
                              void* d_out, int out_size, void* d_ws, size_t ws_size,
                              hipStream_t stream)
{
    (void)in_sizes; (void)n_in; (void)out_size;
    char* ws = (char*)d_ws;
    double* acc = (double*)ws;
    unsigned int* fl = (unsigned int*)(ws + FLAG_OFF);
    float* dWt  = (float*)(ws + DWT_OFF);
    float* St   = (float*)(ws + ST_OFF);
    const bool tr = ws_size >= WS_NEED;

    KP p;
    p.Wraw = (const float*)d_in[0];  p.Sraw = (const float*)d_in[1];
    p.dWt = dWt; p.St = St; p.acc = acc; p.fl = fl; p.out = (float*)d_out;
    p.y0i = (const float*)d_in[2];   p.y1i = (const float*)d_in[3];
    p.z0i = (const float*)d_in[4];   p.z1i = (const float*)d_in[5];
    p.g0 = (const float*)d_in[6];    p.b0 = (const float*)d_in[7];
    p.W0 = (const float*)d_in[8];    p.g1 = (const float*)d_in[9];
    p.b1 = (const float*)d_in[10];   p.W1 = (const float*)d_in[11];
    p.g2 = (const float*)d_in[12];   p.b2 = (const float*)d_in[13];
    p.W2 = (const float*)d_in[14];   p.bias2 = (const float*)d_in[15];
    p.g3 = (const float*)d_in[16];   p.b3 = (const float*)d_in[17];

    kinit<<<98, 256, 0, stream>>>(acc);
    if (tr) {
        ktrans<<<NB/64, 256, 0, stream>>>(p.Wraw, dWt, 1);
        ktrans<<<NB/64, 256, 0, stream>>>(p.Sraw, St, 0);
    }

    void (*kfun)(KP) = tr ? kmain<true> : kmain<false>;
    void* args[] = { (void*)&p };
    hipError_t err = hipLaunchCooperativeKernel((const void*)kfun, dim3(BLOCKS),
                                                dim3(TPB), args, 0, stream);
    if (err != hipSuccess) {
        // fallback: proven multi-kernel path (round-2 flat acc layout).
        float4* state;
        float*  h2pre;
        bool fb_tr = tr && ws_size >= (size_t)H2_OFF + (size_t)NB*16 + (size_t)11*NB*4;
        if (fb_tr) {
            state = (float4*)(ws + H2_OFF);
            h2pre = (float*)(ws + H2_OFF + (size_t)NB * 16);
        } else {
            state = (float4*)(ws + DWT_OFF);
            h2pre = (float*)(ws + DWT_OFF + (size_t)NB * 16);
        }
        dim3 grid(NB/256), blk(256);
        for (int t = 0; t < NSTEP; ++t) {
            if (fb_tr) kA<true ><<<grid, blk, 0, stream>>>(p.Wraw, p.Sraw, dWt, St, state, acc, t, p.g3, p.b3, p.y0i, p.y1i, p.z0i, p.z1i);
            else       kA<false><<<grid, blk, 0, stream>>>(p.Wraw, p.Sraw, dWt, St, state, acc, t, p.g3, p.b3, p.y0i, p.y1i, p.z0i, p.z1i);
            kB<<<grid, blk, 0, stream>>>(state, h2pre, acc, t, p.g0, p.b0, p.W0, p.g1, p.b1, p.W1);
            kC<<<grid, blk, 0, stream>>>(h2pre, acc, t, p.g2, p.b2, p.W2, p.bias2);
        }
        if (fb_tr) kF<true ><<<grid, blk, 0, stream>>>(p.Wraw, p.Sraw, dWt, St, state, p.out, acc, p.g3, p.b3);
        else       kF<false><<<grid, blk, 0, stream>>>(p.Wraw, p.Sraw, dWt, St, state, p.out, acc, p.g3, p.b3);
    }
}

// Round 14
// 1491.937 us; speedup vs baseline: 2.9130x; 1.0078x over previous
//
#include <hip/hip_runtime.h>
#include <hip/hip_cooperative_groups.h>

namespace cg = cooperative_groups;

#define NB 262144
#define NT 64
#define NSTEP 63
#define DTF (1.0f/64.0f)
#define DTD (1.0/64.0)
#define RRF 0.05f
#define INV_B (1.0/262144.0)
#define ACC_STRIDE 48
#define NSL 8
#define BLOCKS 256
#define TPB 256
#define PPT 4
#define PSTRIDE (BLOCKS*TPB)   // 65536, 4 paths/thread

// ws layout (bytes)
#define ACC_BYTES   196608                      // 64*8*48 doubles
#define FLAG_OFF    ACC_BYTES
#define FLAG_BYTES  8192                        // 32 arrival ctrs + 8 release words (64B apart)
#define DWT_OFF     (FLAG_OFF + FLAG_BYTES)
#define DWT_BYTES   (63*NB*4)
#define ST_OFF      (DWT_OFF + DWT_BYTES)
#define ST_BYTES    (64*NB*4)
#define H2_OFF      (ST_OFF + ST_BYTES)          // fallback-only scratch
#define WS_NEED     ((size_t)ST_OFF + (size_t)ST_BYTES)

#define ALOADD(p) __hip_atomic_load((double*)(p), __ATOMIC_RELAXED, __HIP_MEMORY_SCOPE_AGENT)

struct KP {
    const float *Wraw, *Sraw, *dWt, *St;
    double* acc; unsigned int* fl; float* out;
    const float *g0,*b0,*W0,*g1,*b1,*W1,*g2,*b2,*W2,*bias2,*g3,*b3;
    const float *y0i,*y1i,*z0i,*z1i;
};

__global__ void kinit(double* __restrict__ z) {
    int i = blockIdx.x * 256 + threadIdx.x;
    if (i < (int)((ACC_BYTES + FLAG_BYTES) / 8)) z[i] = 0.0;
}

__global__ __launch_bounds__(256) void ktrans(const float* __restrict__ in,
                                              float* __restrict__ out, int diffmode) {
    __shared__ float tile[64][65];
    const int b0 = blockIdx.x * 64;
    const int tx = threadIdx.x & 63;
    const int ty = threadIdx.x >> 6;
    #pragma unroll
    for (int i = 0; i < 16; ++i) {
        int p = ty * 16 + i;
        tile[p][tx] = in[(size_t)(b0 + p) * NT + tx];
    }
    __syncthreads();
    if (diffmode) {
        #pragma unroll
        for (int i = 0; i < 16; ++i) {
            int tt = ty * 16 + i;
            if (tt < 63) out[(size_t)tt * NB + b0 + tx] = tile[tx][tt + 1] - tile[tx][tt];
        }
    } else {
        #pragma unroll
        for (int i = 0; i < 16; ++i) {
            int tt = ty * 16 + i;
            out[(size_t)tt * NB + b0 + tx] = tile[tx][tt];
        }
    }
}

// block-level reduce of K doubles, one f64 atomic per value into block's slice.
template<int K>
__device__ __forceinline__ void bred(const double* v, double (*red)[22],
                                     double* target, int tid) {
    const int lane = tid & 63;
    const int wave = tid >> 6;
    #pragma unroll
    for (int k = 0; k < K; ++k) {
        double x = v[k];
        #pragma unroll
        for (int off = 32; off > 0; off >>= 1) x += __shfl_xor(x, off, 64);
        if (lane == 0) red[wave][k] = x;
    }
    __syncthreads();
    if (tid < K) {
        double s = red[0][tid] + red[1][tid] + red[2][tid] + red[3][tid];
        atomicAdd(&target[tid], s);
    }
}

// Grid barrier, release-fence-at-arrival only (r13-proven consistency).
// r14 micro-opts: 32 arrival counters (8 increments each — 4x less RMW
// serialization than 8x32), NO publication fence (leader's load->branch->
// store control dep orders detection before release), s_sleep(1) polls.
__device__ __forceinline__ void gbar(unsigned int* fl, unsigned int gen) {
    __syncthreads();
    if (threadIdx.x == 0) {
        __builtin_amdgcn_fence(__ATOMIC_RELEASE, "agent");
        __hip_atomic_fetch_add(&fl[(blockIdx.x & 31) * 16], 1u,
                               __ATOMIC_RELAXED, __HIP_MEMORY_SCOPE_AGENT);
    }
    if (blockIdx.x == 0) {
        if (threadIdx.x < 64) {
            for (;;) {
                unsigned int c = __hip_atomic_load(&fl[(threadIdx.x & 31) * 16],
                    __ATOMIC_RELAXED, __HIP_MEMORY_SCOPE_AGENT);
                if (__all(c >= gen * 8u)) break;
                __builtin_amdgcn_s_sleep(1);
            }
            asm volatile("" ::: "memory");
            if (threadIdx.x < 8)
                __hip_atomic_store(&fl[512 + threadIdx.x * 16], gen,
                                   __ATOMIC_RELAXED, __HIP_MEMORY_SCOPE_AGENT);
        }
    } else if (threadIdx.x == 0) {
        const int rw = 512 + (blockIdx.x & 7) * 16;
        while (__hip_atomic_load(&fl[rw], __ATOMIC_RELAXED,
                                 __HIP_MEMORY_SCOPE_AGENT) < gen)
            __builtin_amdgcn_s_sleep(1);
        asm volatile("" ::: "memory");
    }
    __syncthreads();
}

// ================= persistent single-kernel path =================
// 2 barriers/step: phase-A moments are reconstructed analytically from 20
// symbolic sums (state update is affine in z0,z1) reduced during prior C.

template<bool TR>
__global__ __launch_bounds__(256) void kmain(KP p) {
    const int tid = threadIdx.x;
    const int bid = blockIdx.x;
    const int gid = bid * TPB + tid;
    const int sl  = bid & (NSL - 1);
    double* acc = p.acc;
    unsigned int gen = 0;
    #define ACCS(t, q) (acc + ((size_t)(t) * NSL + (q)) * ACC_STRIDE)

    __shared__ float  cf[64];
    __shared__ double red[4][22];
    __shared__ double asum[24];

    float x0[PPT], x1[PPT], y0[PPT], y1[PPT];
    float A0[PPT], A1[PPT], A2[PPT], A3[PPT];
    float dwr[PPT], sr[PPT];
    float h2p[PPT][11];

    // ---------- prologue: step-0 update with z_init + direct 14-moment reduce ----------
    {
        const float z0f = p.z0i[0], z1f = p.z1i[0];
        const float yi0 = p.y0i[0], yi1 = p.y1i[0];
        double v14[14];
        #pragma unroll
        for (int k = 0; k < 14; ++k) v14[k] = 0.0;
        #pragma unroll
        for (int pp = 0; pp < PPT; ++pp) {
            const int pb = gid + pp * PSTRIDE;
            float dw, s;
            if (TR) { dw = p.dWt[pb]; s = p.St[pb]; }
            else {
                const float* wr = p.Wraw + (size_t)pb * NT;
                dw = wr[1] - wr[0]; s = p.Sraw[(size_t)pb * NT];
            }
            dwr[pp] = dw; sr[pp] = s;
            float ox0 = 1.f, ox1 = 0.f, oy0 = yi0, oy1 = yi1;
            float x0n = ox0 + (0.05f*s*ox0 + 0.01f*s*ox1)*DTF
                            + (0.2f*s*ox0 + 0.1f*s*ox1)*dw;
            float y0n = oy0 + RRF*oy0*DTF + z0f*dw;
            float y1n = oy1 + RRF*oy1*DTF + z1f*dw;
            float x1n = ox1 - y1n*DTF;
            x0[pp] = x0n; x1[pp] = x1n; y0[pp] = y0n; y1[pp] = y1n;
            double d0 = x0n, d1 = x1n, d2 = y0n, d3 = y1n;
            v14[0] += d0;    v14[1] += d1;    v14[2] += d2;    v14[3] += d3;
            v14[4] += d0*d0; v14[5] += d0*d1; v14[6] += d0*d2; v14[7] += d0*d3;
            v14[8] += d1*d1; v14[9] += d1*d2; v14[10]+= d1*d3;
            v14[11]+= d2*d2; v14[12]+= d2*d3; v14[13]+= d3*d3;
        }
        bred<14>(v14, red, ACCS(0, sl), tid);
        gbar(p.fl, ++gen);
    }

    #pragma unroll 1
    for (int t = 0; t < NSTEP; ++t) {
        // ---------- phase B: stage sums -> (reconstruct) -> coefs -> h1/h2pre + 22 reduce ----------
        if (t == 0) {
            if (tid < 14) {
                double s = 0.0;
                #pragma unroll
                for (int q = 0; q < NSL; ++q) s += ALOADD(ACCS(0,q) + tid);
                asum[tid] = s;
            }
        } else {
            if (tid < 22) {
                double s = 0.0;
                #pragma unroll
                for (int q = 0; q < NSL; ++q) s += ALOADD(ACCS(t,q) + tid);
                asum[tid] = s;
            } else if (tid == 22) asum[22] = ALOADD(ACCS(t,0) + 44);
            else if   (tid == 23) asum[23] = ALOADD(ACCS(t,0) + 45);
        }
        __syncthreads();
        if (tid < 12) {
            double M1[4], P[10];
            if (t == 0) {
                #pragma unroll
                for (int i = 0; i < 4; ++i) M1[i] = asum[i];
                #pragma unroll
                for (int k = 0; k < 10; ++k) P[k] = asum[4 + k];
            } else {
                double m3 = asum[20] * INV_B;
                double v3 = asum[21] * INV_B - m3 * m3; v3 = v3 < 0.0 ? 0.0 : v3;
                double r3 = 1.0 / sqrt(v3 + 1e-6);
                double g  = (double)p.g3[t-1], bb = (double)p.b3[t-1];
                double z0d = g * (asum[22] - m3) * r3 + bb;
                double z1d = g * (asum[23] - m3) * r3 + bb;
                if (tid == 0) { cf[62] = (float)z0d; cf[63] = (float)z1d; }
                double Sd = asum[18], Sd2 = asum[19];
                M1[0] = asum[0];
                M1[1] = asum[1] - z1d*DTD*Sd;
                M1[2] = asum[2] + z0d*Sd;
                M1[3] = asum[3] + z1d*Sd;
                P[0] = asum[4];
                P[1] = asum[5] - z1d*DTD*asum[14];
                P[2] = asum[6] + z0d*asum[14];
                P[3] = asum[7] + z1d*asum[14];
                P[4] = asum[8] - 2.0*z1d*DTD*asum[15] + z1d*z1d*DTD*DTD*Sd2;
                P[5] = asum[9] + z0d*asum[15] - z1d*DTD*asum[16] - z0d*z1d*DTD*Sd2;
                P[6] = asum[10] + z1d*asum[15] - z1d*DTD*asum[17] - z1d*z1d*DTD*Sd2;
                P[7] = asum[11] + 2.0*z0d*asum[16] + z0d*z0d*Sd2;
                P[8] = asum[12] + z1d*asum[16] + z0d*asum[17] + z0d*z1d*Sd2;
                P[9] = asum[13] + 2.0*z1d*asum[17] + z1d*z1d*Sd2;
            }
            double m[4];
            #pragma unroll
            for (int i = 0; i < 4; ++i) m[i] = M1[i] * INV_B;
            double C[4][4];
            {
                int pidx = 0;
                #pragma unroll
                for (int i = 0; i < 4; ++i)
                    #pragma unroll
                    for (int k = i; k < 4; ++k) {
                        double c = P[pidx++] * INV_B - m[i] * m[k];
                        C[i][k] = c; C[k][i] = c;
                    }
            }
            double u[4];
            #pragma unroll
            for (int i = 0; i < 4; ++i) {
                double vi = C[i][i]; vi = vi < 0.0 ? 0.0 : vi;
                u[i] = (double)p.g0[(size_t)t*4 + i] / sqrt(vi + 1e-6);
            }
            if (tid == 11) {
                #pragma unroll
                for (int i = 0; i < 4; ++i) {
                    cf[0 + i] = (float)u[i];
                    cf[4 + i] = (float)m[i];
                    cf[8 + i] = p.b0[(size_t)t*4 + i];
                }
            } else {
                const int j = tid;
                const float* w0 = p.W0 + (size_t)t * 44;
                double mj = 0.0, vj = 0.0;
                #pragma unroll
                for (int i = 0; i < 4; ++i) {
                    double wij = (double)w0[i*11 + j];
                    mj += (double)p.b0[(size_t)t*4 + i] * wij;
                    double ti = 0.0;
                    #pragma unroll
                    for (int k = 0; k < 4; ++k) ti += u[i]*u[k]*C[i][k]*(double)w0[k*11 + j];
                    vj += wij * ti;
                }
                vj = vj < 0.0 ? 0.0 : vj;
                cf[12 + j] = (float)mj;
                cf[23 + j] = (float)((double)p.g1[(size_t)t*11 + j] / sqrt(vj + 1e-6));
                cf[34 + j] = p.b1[(size_t)t*11 + j];
            }
        }
        __syncthreads();
        if (t > 0) {
            const float zf0 = cf[62], zf1 = cf[63];
            #pragma unroll
            for (int pp = 0; pp < PPT; ++pp) {
                x0[pp] = A0[pp];
                y0[pp] = A2[pp] + zf0 * dwr[pp];
                y1[pp] = A3[pp] + zf1 * dwr[pp];
                x1[pp] = A1[pp] - zf1 * DTF * dwr[pp];
            }
        }
        {
            const float* w0 = p.W0 + (size_t)t * 44;
            const float* w1 = p.W1 + (size_t)t * 121;
            double v22[22];
            #pragma unroll
            for (int k = 0; k < 22; ++k) v22[k] = 0.0;
            #pragma unroll
            for (int pp = 0; pp < PPT; ++pp) {
                float h0[4] = { cf[0]*(x0[pp]-cf[4]) + cf[8],
                                cf[1]*(x1[pp]-cf[5]) + cf[9],
                                cf[2]*(y0[pp]-cf[6]) + cf[10],
                                cf[3]*(y1[pp]-cf[7]) + cf[11] };
                float h1[11];
                #pragma unroll
                for (int j = 0; j < 11; ++j) {
                    float hp = h0[0]*w0[j] + h0[1]*w0[11+j] + h0[2]*w0[22+j] + h0[3]*w0[33+j];
                    h1[j] = fmaxf(cf[23+j]*(hp - cf[12+j]) + cf[34+j], 0.f);
                }
                #pragma unroll
                for (int j = 0; j < 11; ++j) {
                    float hp = 0.f;
                    #pragma unroll
                    for (int i = 0; i < 11; ++i) hp += h1[i] * w1[i*11 + j];
                    h2p[pp][j] = hp;
                    double hd = hp;
                    v22[j] += hd; v22[11+j] += hd*hd;
                }
            }
            bred<22>(v22, red, ACCS(t, sl) + 22, tid);
        }
        gbar(p.fl, ++gen);

        // ---------- phase C: coefs2 -> h3 + symbolic 20 for step t+1 + h3 stats ----------
        if (tid < 22) {
            double s = 0.0;
            #pragma unroll
            for (int q = 0; q < NSL; ++q) s += ALOADD(ACCS(t,q) + 22 + tid);
            asum[tid] = s;
        }
        __syncthreads();
        if (tid < 11) {
            const int j = tid;
            double mj = asum[j] * INV_B;
            double vj = asum[11 + j] * INV_B - mj*mj; vj = vj < 0.0 ? 0.0 : vj;
            cf[j]      = (float)mj;
            cf[11 + j] = (float)((double)p.g2[(size_t)t*11 + j] / sqrt(vj + 1e-6));
            cf[22 + j] = p.b2[(size_t)t*11 + j];
            cf[33 + j] = p.W2[(size_t)t*11 + j];
            if (j == 0) cf[44] = p.bias2[t];
        }
        __syncthreads();
        {
            float h3v[PPT];
            #pragma unroll
            for (int pp = 0; pp < PPT; ++pp) {
                const int pb = gid + pp * PSTRIDE;
                float h3 = cf[44];
                #pragma unroll
                for (int j = 0; j < 11; ++j)
                    h3 += fmaxf(cf[11+j]*(h2p[pp][j] - cf[j]) + cf[22+j], 0.f) * cf[33+j];
                h3v[pp] = h3;
                if (pb == 0) atomicAdd(ACCS(t+1,0) + 44, (double)h3);
                if (pb == 1) atomicAdd(ACCS(t+1,0) + 45, (double)h3);
            }
            if (t < NSTEP - 1) {
                double v22[22];
                #pragma unroll
                for (int k = 0; k < 22; ++k) v22[k] = 0.0;
                #pragma unroll
                for (int pp = 0; pp < PPT; ++pp) {
                    const int pb = gid + pp * PSTRIDE;
                    float dw, s;
                    if (TR) {
                        dw = p.dWt[(size_t)(t+1) * NB + pb];
                        s  = p.St [(size_t)(t+1) * NB + pb];
                    } else {
                        const float* wr = p.Wraw + (size_t)pb * NT + (t+1);
                        dw = wr[1] - wr[0]; s = p.Sraw[(size_t)pb * NT + (t+1)];
                    }
                    dwr[pp] = dw; sr[pp] = s;
                    float a0 = x0[pp] + (0.05f*s*x0[pp] + 0.01f*s*x1[pp])*DTF
                                      + (0.2f*s*x0[pp] + 0.1f*s*x1[pp])*dw;
                    float a2 = y0[pp] + RRF*y0[pp]*DTF;
                    float a3 = y1[pp] + RRF*y1[pp]*DTF;
                    float a1 = x1[pp] - a3*DTF;
                    A0[pp]=a0; A1[pp]=a1; A2[pp]=a2; A3[pp]=a3;
                    double d0=a0, d1=a1, d2=a2, d3=a3, dd=dw;
                    v22[0] += d0;    v22[1] += d1;    v22[2] += d2;    v22[3] += d3;
                    v22[4] += d0*d0; v22[5] += d0*d1; v22[6] += d0*d2; v22[7] += d0*d3;
                    v22[8] += d1*d1; v22[9] += d1*d2; v22[10]+= d1*d3;
                    v22[11]+= d2*d2; v22[12]+= d2*d3; v22[13]+= d3*d3;
                    v22[14]+= d0*dd; v22[15]+= d1*dd; v22[16]+= d2*dd; v22[17]+= d3*dd;
                    v22[18]+= dd;    v22[19]+= dd*dd;
                    double h3d = h3v[pp];
                    v22[20]+= h3d;   v22[21]+= h3d*h3d;
                }
                bred<22>(v22, red, ACCS(t+1, sl), tid);
            } else {
                double v2[2] = {0.0, 0.0};
                #pragma unroll
                for (int pp = 0; pp < PPT; ++pp) {
                    double h3d = h3v[pp];
                    v2[0] += h3d; v2[1] += h3d*h3d;
                }
                bred<2>(v2, red, ACCS(NSTEP, sl) + 20, tid);
            }
        }
        gbar(p.fl, ++gen);
    }

    // ---------- final half-step ----------
    if (tid == 0) {
        double s20 = 0.0, s21 = 0.0;
        #pragma unroll
        for (int q = 0; q < NSL; ++q) {
            s20 += ALOADD(ACCS(NSTEP,q) + 20);
            s21 += ALOADD(ACCS(NSTEP,q) + 21);
        }
        double m3 = s20 * INV_B;
        double v3 = s21 * INV_B - m3*m3; v3 = v3 < 0.0 ? 0.0 : v3;
        double r3 = 1.0 / sqrt(v3 + 1e-6);
        double g = (double)p.g3[62], bb = (double)p.b3[62];
        cf[0] = (float)(g * (ALOADD(ACCS(NSTEP,0) + 44) - m3) * r3 + bb);
        cf[1] = (float)(g * (ALOADD(ACCS(NSTEP,0) + 45) - m3) * r3 + bb);
    }
    __syncthreads();
    {
        const float z0f = cf[0], z1f = cf[1];
        #pragma unroll
        for (int pp = 0; pp < PPT; ++pp) {
            const int pb = gid + pp * PSTRIDE;
            float dw = dwr[pp];   // inputs(62) retained: W[:,63]-W[:,62]
            float s;
            if (TR) s = p.St[(size_t)63 * NB + pb];
            else    s = p.Sraw[(size_t)pb * NT + 63];
            float x0n = x0[pp] + (0.05f*s*x0[pp] + 0.01f*s*x1[pp])*DTF
                               + (0.2f*s*x0[pp] + 0.1f*s*x1[pp])*dw;
            float y0n = y0[pp] + RRF*y0[pp]*DTF + z0f*dw;
            float y1n = y1[pp] + RRF*y1[pp]*DTF + z1f*(-dw);
            float x1n = x1[pp] - y1n*DTF;
            p.out[pb]          = x0n;
            p.out[NB + pb]     = x1n;
            p.out[2*NB + pb]   = y0n;
            p.out[3*NB + pb]   = y1n;
        }
    }
    #undef ACCS
}

// ================= fallback multi-kernel path (round-2, proven) =================

template<bool TR>
__global__ __launch_bounds__(256) void kA(
    const float* __restrict__ Wraw, const float* __restrict__ Sraw,
    const float* __restrict__ dWt,  const float* __restrict__ St,
    float4* __restrict__ state, double* __restrict__ acc, int t,
    const float* __restrict__ g3, const float* __restrict__ b3,
    const float* __restrict__ y0i, const float* __restrict__ y1i,
    const float* __restrict__ z0i, const float* __restrict__ z1i)
{
    __shared__ double red[4][22];
    const int b = blockIdx.x * 256 + threadIdx.x;
    float dw, s;
    if (TR) { dw = dWt[(size_t)t * NB + b]; s = St[(size_t)t * NB + b]; }
    else {
        const float* wr = Wraw + (size_t)b * NT + t;
        dw = wr[1] - wr[0]; s = Sraw[(size_t)b * NT + t];
    }
    float z0, z1, x0, x1, y0, y1;
    if (t == 0) {
        z0 = z0i[0]; z1 = z1i[0];
        x0 = 1.f; x1 = 0.f; y0 = y0i[0]; y1 = y1i[0];
    } else {
        const double* a = acc + (size_t)(t - 1) * ACC_STRIDE;
        double m3 = a[36] * INV_B;
        double v3 = a[37] * INV_B - m3 * m3; v3 = v3 < 0.0 ? 0.0 : v3;
        double r3 = 1.0 / sqrt(v3 + 1e-6);
        double g  = (double)g3[t - 1], bb = (double)b3[t - 1];
        z0 = (float)(g * (a[38] - m3) * r3 + bb);
        z1 = (float)(g * (a[39] - m3) * r3 + bb);
        float4 s4 = state[b];
        x0 = s4.x; x1 = s4.y; y0 = s4.z; y1 = s4.w;
    }
    float x0n = x0 + (0.05f*s*x0 + 0.01f*s*x1)*DTF + (0.2f*s*x0 + 0.1f*s*x1)*dw;
    float y0n = y0 + RRF*y0*DTF + z0*dw;
    float y1n = y1 + RRF*y1*DTF + z1*dw;
    float x1n = x1 - y1n*DTF;
    state[b] = make_float4(x0n, x1n, y0n, y1n);
    double d0 = x0n, d1 = x1n, d2 = y0n, d3 = y1n;
    double v[14] = { d0, d1, d2, d3,
                     d0*d0, d0*d1, d0*d2, d0*d3,
                     d1*d1, d1*d2, d1*d3,
                     d2*d2, d2*d3, d3*d3 };
    bred<14>(v, red, acc + (size_t)t * ACC_STRIDE, threadIdx.x);
}

__global__ __launch_bounds__(256) void kB(
    const float4* __restrict__ state, float* __restrict__ h2pre,
    double* __restrict__ acc, int t,
    const float* __restrict__ g0, const float* __restrict__ b0,
    const float* __restrict__ W0,
    const float* __restrict__ g1, const float* __restrict__ b1,
    const float* __restrict__ W1)
{
    __shared__ double red[4][22];
    const int b = blockIdx.x * 256 + threadIdx.x;
    float4 s4 = state[b];

    const double* a = acc + (size_t)t * ACC_STRIDE;
    double m[4];
    #pragma unroll
    for (int i = 0; i < 4; ++i) m[i] = a[i] * INV_B;
    double C[4][4];
    {
        int p = 4;
        #pragma unroll
        for (int i = 0; i < 4; ++i)
            #pragma unroll
            for (int k = i; k < 4; ++k) {
                double c = a[p++] * INV_B - m[i] * m[k];
                C[i][k] = c; C[k][i] = c;
            }
    }
    const float* w0 = W0 + (size_t)t * 44;
    float w0f[4][11];
    #pragma unroll
    for (int i = 0; i < 4; ++i)
        #pragma unroll
        for (int j = 0; j < 11; ++j) w0f[i][j] = w0[i * 11 + j];

    double u[4]; float uf[4], mf[4], b0f[4];
    #pragma unroll
    for (int i = 0; i < 4; ++i) {
        double vi = C[i][i]; vi = vi < 0.0 ? 0.0 : vi;
        double ri = 1.0 / sqrt(vi + 1e-6);
        u[i]  = (double)g0[(size_t)t * 4 + i] * ri;
        uf[i] = (float)u[i];
        mf[i] = (float)m[i];
        b0f[i] = b0[(size_t)t * 4 + i];
    }
    double M[4][4];
    #pragma unroll
    for (int i = 0; i < 4; ++i)
        #pragma unroll
        for (int k = 0; k < 4; ++k) M[i][k] = u[i] * u[k] * C[i][k];

    float mean1[11], q1[11], b1f[11];
    #pragma unroll
    for (int j = 0; j < 11; ++j) {
        double mj = 0.0, vj = 0.0;
        #pragma unroll
        for (int i = 0; i < 4; ++i) {
            mj += (double)b0f[i] * (double)w0f[i][j];
            double ti = 0.0;
            #pragma unroll
            for (int k = 0; k < 4; ++k) ti += M[i][k] * (double)w0f[k][j];
            vj += (double)w0f[i][j] * ti;
        }
        vj = vj < 0.0 ? 0.0 : vj;
        double rj = 1.0 / sqrt(vj + 1e-6);
        mean1[j] = (float)mj;
        q1[j]    = (float)((double)g1[(size_t)t * 11 + j] * rj);
        b1f[j]   = b1[(size_t)t * 11 + j];
    }

    float h0[4] = { uf[0]*(s4.x - mf[0]) + b0f[0],
                    uf[1]*(s4.y - mf[1]) + b0f[1],
                    uf[2]*(s4.z - mf[2]) + b0f[2],
                    uf[3]*(s4.w - mf[3]) + b0f[3] };
    float h1[11];
    #pragma unroll
    for (int j = 0; j < 11; ++j) {
        float hp = h0[0]*w0f[0][j] + h0[1]*w0f[1][j] + h0[2]*w0f[2][j] + h0[3]*w0f[3][j];
        h1[j] = fmaxf(q1[j] * (hp - mean1[j]) + b1f[j], 0.f);
    }
    const float* w1 = W1 + (size_t)t * 121;
    double v[22];
    #pragma unroll
    for (int j = 0; j < 11; ++j) {
        float hp = 0.f;
        #pragma unroll
        for (int i = 0; i < 11; ++i) hp += h1[i] * w1[i * 11 + j];
        h2pre[(size_t)j * NB + b] = hp;
        double hd = hp;
        v[j] = hd; v[11 + j] = hd * hd;
    }
    bred<22>(v, red, acc + (size_t)t * ACC_STRIDE + 14, threadIdx.x);
}

__global__ __launch_bounds__(256) void kC(
    const float* __restrict__ h2pre, double* __restrict__ acc, int t,
    const float* __restrict__ g2, const float* __restrict__ b2,
    const float* __restrict__ W2, const float* __restrict__ bias2)
{
    __shared__ double red[4][22];
    const int b = blockIdx.x * 256 + threadIdx.x;
    const double* a = acc + (size_t)t * ACC_STRIDE;
    float m2f[11], q2[11], b2f[11], w2f[11];
    #pragma unroll
    for (int j = 0; j < 11; ++j) {
        double mj = a[14 + j] * INV_B;
        double vj = a[25 + j] * INV_B - mj * mj; vj = vj < 0.0 ? 0.0 : vj;
        double rj = 1.0 / sqrt(vj + 1e-6);
        m2f[j] = (float)mj;
        q2[j]  = (float)((double)g2[(size_t)t * 11 + j] * rj);
        b2f[j] = b2[(size_t)t * 11 + j];
        w2f[j] = W2[(size_t)t * 11 + j];
    }
    float h3 = bias2[t];
    #pragma unroll
    for (int j = 0; j < 11; ++j) {
        float hv = h2pre[(size_t)j * NB + b];
        float h2 = fmaxf(q2[j] * (hv - m2f[j]) + b2f[j], 0.f);
        h3 += h2 * w2f[j];
    }
    double* aw = acc + (size_t)t * ACC_STRIDE;
    if (b == 0) aw[38] = (double)h3;
    if (b == 1) aw[39] = (double)h3;
    double hd = h3;
    double v[2] = { hd, hd * hd };
    bred<2>(v, red, aw + 36, threadIdx.x);
}

template<bool TR>
__global__ __launch_bounds__(256) void kF(
    const float* __restrict__ Wraw, const float* __restrict__ Sraw,
    const float* __restrict__ dWt,  const float* __restrict__ St,
    const float4* __restrict__ state, float* __restrict__ out,
    const double* __restrict__ acc,
    const float* __restrict__ g3, const float* __restrict__ b3)
{
    const int b = blockIdx.x * 256 + threadIdx.x;
    const double* a = acc + (size_t)62 * ACC_STRIDE;
    double m3 = a[36] * INV_B;
    double v3 = a[37] * INV_B - m3 * m3; v3 = v3 < 0.0 ? 0.0 : v3;
    double r3 = 1.0 / sqrt(v3 + 1e-6);
    double g  = (double)g3[62], bb = (double)b3[62];
    float z0 = (float)(g * (a[38] - m3) * r3 + bb);
    float z1 = (float)(g * (a[39] - m3) * r3 + bb);

    float dw, s;
    if (TR) { dw = dWt[(size_t)62 * NB + b]; s = St[(size_t)63 * NB + b]; }
    else {
        const float* wr = Wraw + (size_t)b * NT + 62;
        dw = wr[1] - wr[0]; s = Sraw[(size_t)b * NT + 63];
    }
    float4 s4 = state[b];
    float x0 = s4.x, x1 = s4.y, y0 = s4.z, y1 = s4.w;
    float x0n = x0 + (0.05f*s*x0 + 0.01f*s*x1)*DTF + (0.2f*s*x0 + 0.1f*s*x1)*dw;
    float y0n = y0 + RRF*y0*DTF + z0*dw;
    float y1n = y1 + RRF*y1*DTF + z1*(-dw);
    float x1n = x1 - y1n*DTF;
    out[b]          = x0n;
    out[NB + b]     = x1n;
    out[2*NB + b]   = y0n;
    out[3*NB + b]   = y1n;
}

// ---------------- launcher ----------------

extern "C" void kernel_launch(void* const* d_in, const int* in_sizes, int n_in,
                              void* d_out, int out_size, void* d_ws, size_t ws_size,
                              hipStream_t stream)
{
    (void)in_sizes; (void)n_in; (void)out_size;
    char* ws = (char*)d_ws;
    double* acc = (double*)ws;
    unsigned int* fl = (unsigned int*)(ws + FLAG_OFF);
    float* dWt  = (float*)(ws + DWT_OFF);
    float* St   = (float*)(ws + ST_OFF);
    const bool tr = ws_size >= WS_NEED;

    KP p;
    p.Wraw = (const float*)d_in[0];  p.Sraw = (const float*)d_in[1];
    p.dWt = dWt; p.St = St; p.acc = acc; p.fl = fl; p.out = (float*)d_out;
    p.y0i = (const float*)d_in[2];   p.y1i = (const float*)d_in[3];
    p.z0i = (const float*)d_in[4];   p.z1i = (const float*)d_in[5];
    p.g0 = (const float*)d_in[6];    p.b0 = (const float*)d_in[7];
    p.W0 = (const float*)d_in[8];    p.g1 = (const float*)d_in[9];
    p.b1 = (const float*)d_in[10];   p.W1 = (const float*)d_in[11];
    p.g2 = (const float*)d_in[12];   p.b2 = (const float*)d_in[13];
    p.W2 = (const float*)d_in[14];   p.bias2 = (const float*)d_in[15];
    p.g3 = (const float*)d_in[16];   p.b3 = (const float*)d_in[17];

    kinit<<<101, 256, 0, stream>>>(acc);
    if (tr) {
        ktrans<<<NB/64, 256, 0, stream>>>(p.Wraw, dWt, 1);
        ktrans<<<NB/64, 256, 0, stream>>>(p.Sraw, St, 0);
    }

    void (*kfun)(KP) = tr ? kmain<true> : kmain<false>;
    void* args[] = { (void*)&p };
    hipError_t err = hipLaunchCooperativeKernel((const void*)kfun, dim3(BLOCKS),
                                                dim3(TPB), args, 0, stream);
    if (err != hipSuccess) {
        // fallback: proven multi-kernel path (round-2 flat acc layout).
        float4* state;
        float*  h2pre;
        bool fb_tr = tr && ws_size >= (size_t)H2_OFF + (size_t)NB*16 + (size_t)11*NB*4;
        if (fb_tr) {
            state = (float4*)(ws + H2_OFF);
            h2pre = (float*)(ws + H2_OFF + (size_t)NB * 16);
        } else {
            state = (float4*)(ws + DWT_OFF);
            h2pre = (float*)(ws + DWT_OFF + (size_t)NB * 16);
        }
        dim3 grid(NB/256), blk(256);
        for (int t = 0; t < NSTEP; ++t) {
            if (fb_tr) kA<true ><<<grid, blk, 0, stream>>>(p.Wraw, p.Sraw, dWt, St, state, acc, t, p.g3, p.b3, p.y0i, p.y1i, p.z0i, p.z1i);
            else       kA<false><<<grid, blk, 0, stream>>>(p.Wraw, p.Sraw, dWt, St, state, acc, t, p.g3, p.b3, p.y0i, p.y1i, p.z0i, p.z1i);
            kB<<<grid, blk, 0, stream>>>(state, h2pre, acc, t, p.g0, p.b0, p.W0, p.g1, p.b1, p.W1);
            kC<<<grid, blk, 0, stream>>>(h2pre, acc, t, p.g2, p.b2, p.W2, p.bias2);
        }
        if (fb_tr) kF<true ><<<grid, blk, 0, stream>>>(p.Wraw, p.Sraw, dWt, St, state, p.out, acc, p.g3, p.b3);
        else       kF<false><<<grid, blk, 0, stream>>>(p.Wraw, p.Sraw, dWt, St, state, p.out, acc, p.g3, p.b3);
    }
}